// Round 2
// baseline (4501.909 us; speedup 1.0000x reference)
//
#include <hip/hip_runtime.h>

// ---------------------------------------------------------------------------
// GIN (2 layers) + global mean pool, MI355X (gfx950).
// Dtype-agnostic: on-device detection of float(bf16 vs f32) and int(32 vs 64),
// uniform-branch conversions into canonical bf16/f32 buffers, one compute path.
//
// ws layout:
//   [flags][Wb bias bf16][Wp0..3 packed weights][F32 51.2MB][BB bf16 25.6MB]
// Pipeline:
//   BB=bf16(x); F32=f32(BB); scatter BB->F32 (ld128); BB=bf16(F32)
//   t  = relu(BB @ W1_0 + b1_0)  -> F32-region-as-bf16   (K=128)
//   h1 = relu(t  @ W2_0 + b2_0)  -> BB                   (K=256)
//   F32=f32(BB); scatter BB->F32 (ld256); BB=bf16(F32)
//   t2 = relu(BB @ W1_1 + b1_1)  -> F32-region-as-bf16
//   h2 = relu(t2 @ W2_1 + b2_1)  -> BB
//   out[g,c] = segment-mean of BB over sorted batch (binary search)
// ---------------------------------------------------------------------------

typedef __bf16 bf16x8 __attribute__((ext_vector_type(8)));
typedef float f32x4 __attribute__((ext_vector_type(4)));

#define N_NODES 50000
#define N_EDGES 800000
#define N_GRAPHS 64

#define OFF_FLAGS 0ull
#define OFF_WB    64ull
#define OFF_WP0   4096ull
#define OFF_WP1   (OFF_WP0 + 65536ull)
#define OFF_WP2   (OFF_WP1 + 131072ull)
#define OFF_WP3   (OFF_WP2 + 131072ull)
#define OFF_F32   524288ull
#define OFF_BB    (OFF_F32 + 51200000ull)

__device__ __forceinline__ float b2f(unsigned short u) {
  union { unsigned int i; float f; } v; v.i = ((unsigned int)u) << 16; return v.f;
}
__device__ __forceinline__ unsigned short f2b(float f) {
  union { unsigned int i; float f; } v; v.f = f;
  unsigned int r = v.i + 0x7fffu + ((v.i >> 16) & 1u);
  return (unsigned short)(r >> 16);
}

// ---- dtype detection: flags[0]=floats-are-bf16, flags[1]=ints-are-64bit
__global__ void detect_kernel(const unsigned int* __restrict__ xw,
                              const unsigned int* __restrict__ eiw,
                              int* __restrict__ flags) {
  __shared__ int s_f[256], s_i[256];
  int t = threadIdx.x;
  int fh = 0, iz = 0;
  for (int i = t; i < 1024; i += 256) {
    unsigned int e = (xw[i] >> 7) & 0xFFu;          // bf16: low-elem exponent; f32: mantissa bits
    fh += (e >= 115u && e <= 130u) ? 1 : 0;
    iz += (eiw[2 * i + 1] == 0u) ? 1 : 0;           // int64: hi word always 0
  }
  s_f[t] = fh; s_i[t] = iz;
  __syncthreads();
  for (int s = 128; s > 0; s >>= 1) {
    if (t < s) { s_f[t] += s_f[t + s]; s_i[t] += s_i[t + s]; }
    __syncthreads();
  }
  if (t == 0) { flags[0] = s_f[0] > 512 ? 1 : 0; flags[1] = s_i[0] > 512 ? 1 : 0; }
}

// ---- raw float input -> canonical bf16
__global__ void conv_to_bf16(const void* __restrict__ raw,
                             unsigned short* __restrict__ outb, int n,
                             const int* __restrict__ flags) {
  int i = blockIdx.x * blockDim.x + threadIdx.x;
  if (i >= n) return;
  outb[i] = flags[0] ? ((const unsigned short*)raw)[i]
                     : f2b(((const float*)raw)[i]);
}

// ---- canonical bf16 -> f32 accumulator init (the GIN self-term)
__global__ void b2f_kernel(const unsigned short* __restrict__ in,
                           float* __restrict__ out, int n) {
  int i = blockIdx.x * blockDim.x + threadIdx.x;
  if (i < n) out[i] = b2f(in[i]);
}

// ---- f32 -> canonical bf16
__global__ void f2b_kernel(const float* __restrict__ in,
                           unsigned short* __restrict__ out, int n) {
  int i = blockIdx.x * blockDim.x + threadIdx.x;
  if (i < n) out[i] = f2b(in[i]);
}

// ---- pack W (K x 256 row-major) into MFMA b-frag order, dtype-aware read.
// Wp[((kb*256 + n)*4 + q)*8 + j] = W[kb*32 + q*8 + j][n]
__global__ void pack_w(const void* __restrict__ W,
                       unsigned short* __restrict__ Wp, int K,
                       const int* __restrict__ flags) {
  int tid = blockIdx.x * blockDim.x + threadIdx.x;
  int total = (K >> 5) << 10;
  if (tid >= total) return;
  int q = tid & 3;
  int n = (tid >> 2) & 255;
  int kb = tid >> 10;
  int krow = (kb << 5) + (q << 3);
  int isb = flags[0];
  unsigned short* o = Wp + (size_t)tid * 8;
#pragma unroll
  for (int j = 0; j < 8; ++j) {
    size_t idx = (size_t)(krow + j) * 256 + n;
    o[j] = isb ? ((const unsigned short*)W)[idx] : f2b(((const float*)W)[idx]);
  }
}

// ---- pack 4 biases into canonical bf16 Wb[l*256 + n]
__global__ void pack_bias(const void* b0, const void* b1, const void* b2, const void* b3,
                          unsigned short* __restrict__ Wb,
                          const int* __restrict__ flags) {
  int t = blockIdx.x * blockDim.x + threadIdx.x;  // 1024
  if (t >= 1024) return;
  const void* p = (t < 256) ? b0 : (t < 512) ? b1 : (t < 768) ? b2 : b3;
  int n = t & 255;
  Wb[t] = flags[0] ? ((const unsigned short*)p)[n] : f2b(((const float*)p)[n]);
}

// ---- scatter: acc[dst][:] += feat[src][:]; thread = (edge, 4-col group)
__global__ void scatter_add(const unsigned short* __restrict__ feat,
                            const int* __restrict__ ei,
                            float* __restrict__ acc, int logG,
                            const int* __restrict__ flags) {
  int tid = blockIdx.x * blockDim.x + threadIdx.x;
  int e = tid >> logG;
  if (e >= N_EDGES) return;
  int G = 1 << logG;
  int g = tid & (G - 1);
  int ld = G << 2;
  int is64 = flags[1];
  int src = is64 ? ei[2 * e] : ei[e];
  int dst = is64 ? ei[2 * (N_EDGES + e)] : ei[N_EDGES + e];
  const ushort4 v = *(const ushort4*)(feat + (size_t)src * ld + (g << 2));
  float* p = acc + (size_t)dst * ld + (g << 2);
  unsafeAtomicAdd(p + 0, b2f(v.x));
  unsafeAtomicAdd(p + 1, b2f(v.y));
  unsafeAtomicAdd(p + 2, b2f(v.z));
  unsafeAtomicAdd(p + 3, b2f(v.w));
}

// ---- C(M x 256) = relu(A(M x K) @ W + b), bf16 out.
// Block=256thr=4 waves; tile 16 rows x 256 cols; wave w -> cols [64w, 64w+64).
__global__ void gemm_relu(const unsigned short* __restrict__ A,
                          const unsigned short* __restrict__ Wp,
                          const unsigned short* __restrict__ Wb, int bias_row,
                          unsigned short* __restrict__ C, int K) {
  const int row0 = blockIdx.x << 4;
  const int lane = threadIdx.x & 63;
  const int wave = threadIdx.x >> 6;
  const int m = lane & 15;
  const int q = lane >> 4;
  f32x4 acc[4];
#pragma unroll
  for (int t = 0; t < 4; ++t) acc[t] = (f32x4){0.f, 0.f, 0.f, 0.f};

  const unsigned short* arow = A + (size_t)(row0 + m) * K + (q << 3);
  const int nb = (wave << 6) + m;
  const int kblocks = K >> 5;
  for (int kb = 0; kb < kblocks; ++kb) {
    bf16x8 af = *(const bf16x8*)(arow + (kb << 5));
    const unsigned short* wp = Wp + (((size_t)(kb << 8) + nb) * 4 + q) * 8;
    bf16x8 b0 = *(const bf16x8*)(wp);
    bf16x8 b1 = *(const bf16x8*)(wp + 512);
    bf16x8 b2 = *(const bf16x8*)(wp + 1024);
    bf16x8 b3 = *(const bf16x8*)(wp + 1536);
    acc[0] = __builtin_amdgcn_mfma_f32_16x16x32_bf16(af, b0, acc[0], 0, 0, 0);
    acc[1] = __builtin_amdgcn_mfma_f32_16x16x32_bf16(af, b1, acc[1], 0, 0, 0);
    acc[2] = __builtin_amdgcn_mfma_f32_16x16x32_bf16(af, b2, acc[2], 0, 0, 0);
    acc[3] = __builtin_amdgcn_mfma_f32_16x16x32_bf16(af, b3, acc[3], 0, 0, 0);
  }
#pragma unroll
  for (int t = 0; t < 4; ++t) {
    int n = (wave << 6) + (t << 4) + m;
    float bv = b2f(Wb[bias_row * 256 + n]);
#pragma unroll
    for (int i = 0; i < 4; ++i) {
      int r = row0 + (q << 2) + i;
      float v = fmaxf(acc[t][i] + bv, 0.f);
      C[(size_t)r * 256 + n] = f2b(v);
    }
  }
}

// ---- mean pool: batch sorted; binary search bounds; dtype-aware out + batch
__device__ __forceinline__ int lower_bound(const int* a, int n, int v, int is64) {
  int lo = 0, hi = n;
  while (lo < hi) {
    int mid = (lo + hi) >> 1;
    int bv = is64 ? a[2 * mid] : a[mid];
    if (bv < v) lo = mid + 1; else hi = mid;
  }
  return lo;
}

__global__ void pool_kernel(const unsigned short* __restrict__ h2,
                            const int* __restrict__ batch,
                            void* __restrict__ out,
                            const int* __restrict__ flags) {
  __shared__ int sh[2];
  int g = blockIdx.x;
  int is64 = flags[1];
  if (threadIdx.x == 0) sh[0] = lower_bound(batch, N_NODES, g, is64);
  if (threadIdx.x == 1) sh[1] = lower_bound(batch, N_NODES, g + 1, is64);
  __syncthreads();
  int s = sh[0], e = sh[1];
  int c = threadIdx.x;
  float acc = 0.f;
  for (int r = s; r < e; ++r) acc += b2f(h2[(size_t)r * 256 + c]);
  float res = acc / fmaxf((float)(e - s), 1.0f);
  if (flags[0]) ((unsigned short*)out)[(size_t)g * 256 + c] = f2b(res);
  else          ((float*)out)[(size_t)g * 256 + c] = res;
}

extern "C" void kernel_launch(void* const* d_in, const int* in_sizes, int n_in,
                              void* d_out, int out_size, void* d_ws, size_t ws_size,
                              hipStream_t stream) {
  const void* x    = d_in[0];
  const int*  ei   = (const int*)d_in[1];
  const int*  batch= (const int*)d_in[2];
  const void* W1_0 = d_in[3];
  const void* b1_0 = d_in[4];
  const void* W2_0 = d_in[5];
  const void* b2_0 = d_in[6];
  const void* W1_1 = d_in[7];
  const void* b1_1 = d_in[8];
  const void* W2_1 = d_in[9];
  const void* b2_1 = d_in[10];

  char* ws = (char*)d_ws;
  int*            flags = (int*)(ws + OFF_FLAGS);
  unsigned short* Wb    = (unsigned short*)(ws + OFF_WB);
  unsigned short* Wp0   = (unsigned short*)(ws + OFF_WP0);
  unsigned short* Wp1   = (unsigned short*)(ws + OFF_WP1);
  unsigned short* Wp2   = (unsigned short*)(ws + OFF_WP2);
  unsigned short* Wp3   = (unsigned short*)(ws + OFF_WP3);
  float*          F32   = (float*)(ws + OFF_F32);
  unsigned short* TB    = (unsigned short*)(ws + OFF_F32);  // bf16 alias of F32 region
  unsigned short* BB    = (unsigned short*)(ws + OFF_BB);

  detect_kernel<<<1, 256, 0, stream>>>((const unsigned int*)x, (const unsigned int*)ei, flags);

  pack_w<<<16, 256, 0, stream>>>(W1_0, Wp0, 128, flags);
  pack_w<<<32, 256, 0, stream>>>(W2_0, Wp1, 256, flags);
  pack_w<<<32, 256, 0, stream>>>(W1_1, Wp2, 256, flags);
  pack_w<<<32, 256, 0, stream>>>(W2_1, Wp3, 256, flags);
  pack_bias<<<4, 256, 0, stream>>>(b1_0, b2_0, b1_1, b2_1, Wb, flags);

  // ---- layer 1 (128 cols)
  conv_to_bf16<<<25000, 256, 0, stream>>>(x, BB, 6400000, flags);
  b2f_kernel<<<25000, 256, 0, stream>>>(BB, F32, 6400000);
  scatter_add<<<100000, 256, 0, stream>>>(BB, ei, F32, 5, flags);
  f2b_kernel<<<25000, 256, 0, stream>>>(F32, BB, 6400000);
  gemm_relu<<<3125, 256, 0, stream>>>(BB, Wp0, Wb, 0, TB, 128);   // t  -> F32-as-bf16
  gemm_relu<<<3125, 256, 0, stream>>>(TB, Wp1, Wb, 1, BB, 256);   // h1 -> BB

  // ---- layer 2 (256 cols)
  b2f_kernel<<<50000, 256, 0, stream>>>(BB, F32, 12800000);
  scatter_add<<<200000, 256, 0, stream>>>(BB, ei, F32, 6, flags);
  f2b_kernel<<<50000, 256, 0, stream>>>(F32, BB, 12800000);
  gemm_relu<<<3125, 256, 0, stream>>>(BB, Wp2, Wb, 2, TB, 256);   // t2 -> F32-as-bf16
  gemm_relu<<<3125, 256, 0, stream>>>(TB, Wp3, Wb, 3, BB, 256);   // h2 -> BB

  // ---- global mean pool
  pool_kernel<<<N_GRAPHS, 256, 0, stream>>>(BB, batch, d_out, flags);
}

// Round 3
// 879.959 us; speedup vs baseline: 5.1160x; 5.1160x over previous
//
#include <hip/hip_runtime.h>

// ---------------------------------------------------------------------------
// GIN (2 layers) + global mean pool, MI355X (gfx950).
// R3: replace fp32-atomic scatter (3.9ms of 4.5ms) with on-device CSR
// (counting sort by dst) + register-accumulated gather-reduce. No f32
// intermediate buffer; gathers read bf16 and write bf16 (one f32->bf16 round,
// same numerics as before).
//
// ws: [flags][Wb][Wp0..3][counts][rowptr][cursor][ssrc u16][A 12.8M][B 25.6M][C 25.6M]
// Pipeline:
//   CSR build (hist -> scan -> fill)            [once, reused by both layers]
//   A = bf16(x)
//   B1 = gather(A)           (self + neighbors, D=128)
//   C = relu(B1 @ W1_0 + b)  (K=128)   B = relu(C @ W2_0 + b)   (h1)
//   C = gather(B)            (D=256)
//   B = relu(C @ W1_1 + b)              C = relu(B @ W2_1 + b)  (h2)
//   out = segment-mean(C) over sorted batch
// ---------------------------------------------------------------------------

typedef __bf16 bf16x8 __attribute__((ext_vector_type(8)));
typedef float f32x4 __attribute__((ext_vector_type(4)));

#define N_NODES 50000
#define N_EDGES 800000
#define N_GRAPHS 64

#define OFF_FLAGS  0ull
#define OFF_WB     64ull
#define OFF_WP0    4096ull
#define OFF_WP1    (OFF_WP0 + 65536ull)
#define OFF_WP2    (OFF_WP1 + 131072ull)
#define OFF_WP3    (OFF_WP2 + 131072ull)
#define OFF_CNT    462848ull
#define OFF_ROWPTR 662864ull
#define OFF_CURSOR 862880ull
#define OFF_SSRC   1062912ull
#define OFF_A      2662912ull               // 12.8 MB
#define OFF_B      15462912ull              // 25.6 MB
#define OFF_C      41062912ull              // 25.6 MB  (end ~66.7 MB)

__device__ __forceinline__ float b2f(unsigned short u) {
  union { unsigned int i; float f; } v; v.i = ((unsigned int)u) << 16; return v.f;
}
__device__ __forceinline__ unsigned short f2b(float f) {
  union { unsigned int i; float f; } v; v.f = f;
  unsigned int r = v.i + 0x7fffu + ((v.i >> 16) & 1u);
  return (unsigned short)(r >> 16);
}

// ---- dtype detection: flags[0]=floats-are-bf16, flags[1]=ints-are-64bit
__global__ void detect_kernel(const unsigned int* __restrict__ xw,
                              const unsigned int* __restrict__ eiw,
                              int* __restrict__ flags) {
  __shared__ int s_f[256], s_i[256];
  int t = threadIdx.x;
  int fh = 0, iz = 0;
  for (int i = t; i < 1024; i += 256) {
    unsigned int e = (xw[i] >> 7) & 0xFFu;
    fh += (e >= 115u && e <= 130u) ? 1 : 0;
    iz += (eiw[2 * i + 1] == 0u) ? 1 : 0;
  }
  s_f[t] = fh; s_i[t] = iz;
  __syncthreads();
  for (int s = 128; s > 0; s >>= 1) {
    if (t < s) { s_f[t] += s_f[t + s]; s_i[t] += s_i[t + s]; }
    __syncthreads();
  }
  if (t == 0) { flags[0] = s_f[0] > 512 ? 1 : 0; flags[1] = s_i[0] > 512 ? 1 : 0; }
}

// ---- raw float input -> canonical bf16
__global__ void conv_to_bf16(const void* __restrict__ raw,
                             unsigned short* __restrict__ outb, int n,
                             const int* __restrict__ flags) {
  int i = blockIdx.x * blockDim.x + threadIdx.x;
  if (i >= n) return;
  outb[i] = flags[0] ? ((const unsigned short*)raw)[i]
                     : f2b(((const float*)raw)[i]);
}

// ---- pack W (K x 256 row-major) into MFMA b-frag order, dtype-aware read.
__global__ void pack_w(const void* __restrict__ W,
                       unsigned short* __restrict__ Wp, int K,
                       const int* __restrict__ flags) {
  int tid = blockIdx.x * blockDim.x + threadIdx.x;
  int total = (K >> 5) << 10;
  if (tid >= total) return;
  int q = tid & 3;
  int n = (tid >> 2) & 255;
  int kb = tid >> 10;
  int krow = (kb << 5) + (q << 3);
  int isb = flags[0];
  unsigned short* o = Wp + (size_t)tid * 8;
#pragma unroll
  for (int j = 0; j < 8; ++j) {
    size_t idx = (size_t)(krow + j) * 256 + n;
    o[j] = isb ? ((const unsigned short*)W)[idx] : f2b(((const float*)W)[idx]);
  }
}

__global__ void pack_bias(const void* b0, const void* b1, const void* b2, const void* b3,
                          unsigned short* __restrict__ Wb,
                          const int* __restrict__ flags) {
  int t = blockIdx.x * blockDim.x + threadIdx.x;
  if (t >= 1024) return;
  const void* p = (t < 256) ? b0 : (t < 512) ? b1 : (t < 768) ? b2 : b3;
  int n = t & 255;
  Wb[t] = flags[0] ? ((const unsigned short*)p)[n] : f2b(((const float*)p)[n]);
}

// ---- CSR build -----------------------------------------------------------
__global__ void zero_counts(int* __restrict__ counts) {
  int i = blockIdx.x * blockDim.x + threadIdx.x;
  if (i < N_NODES) counts[i] = 0;
}

__global__ void hist_kernel(const int* __restrict__ ei, int* __restrict__ counts,
                            const int* __restrict__ flags) {
  int e = blockIdx.x * blockDim.x + threadIdx.x;
  if (e >= N_EDGES) return;
  int is64 = flags[1];
  int dst = is64 ? ei[2 * (N_EDGES + e)] : ei[N_EDGES + e];
  atomicAdd(&counts[dst], 1);
}

// single block, 1024 threads: exclusive scan of counts -> rowptr + cursor
__global__ void scan_kernel(const int* __restrict__ counts,
                            int* __restrict__ rowptr, int* __restrict__ cursor) {
  __shared__ int sdata[1024];
  const int CH = 49;  // 1024*49 >= 50000
  int t = threadIdx.x;
  int lo = t * CH;
  int sum = 0;
  for (int i = lo; i < lo + CH && i < N_NODES; ++i) sum += counts[i];
  sdata[t] = sum;
  __syncthreads();
  for (int off = 1; off < 1024; off <<= 1) {
    int v = (t >= off) ? sdata[t - off] : 0;
    __syncthreads();
    sdata[t] += v;
    __syncthreads();
  }
  int run = sdata[t] - sum;  // exclusive prefix of this chunk
  for (int i = lo; i < lo + CH && i < N_NODES; ++i) {
    rowptr[i] = run; cursor[i] = run;
    run += counts[i];
  }
  if (t == 1023) rowptr[N_NODES] = sdata[1023];
}

__global__ void fill_kernel(const int* __restrict__ ei, int* __restrict__ cursor,
                            unsigned short* __restrict__ ssrc,
                            const int* __restrict__ flags) {
  int e = blockIdx.x * blockDim.x + threadIdx.x;
  if (e >= N_EDGES) return;
  int is64 = flags[1];
  int src = is64 ? ei[2 * e] : ei[e];
  int dst = is64 ? ei[2 * (N_EDGES + e)] : ei[N_EDGES + e];
  int pos = atomicAdd(&cursor[dst], 1);
  ssrc[pos] = (unsigned short)src;
}

// ---- gather-reduce: out[n][:] = feat[n][:] + sum_{src in N(n)} feat[src][:]
// thread handles 2 cols (ushort2); D=128 -> 4 nodes/block, D=256 -> 2.
__global__ void gather_kernel(const unsigned short* __restrict__ feat,
                              const int* __restrict__ rowptr,
                              const unsigned short* __restrict__ ssrc,
                              unsigned short* __restrict__ out, int D) {
  int tpn = D >> 1;                       // threads per node
  int npb = 256 / tpn;                    // nodes per block
  int node = blockIdx.x * npb + threadIdx.x / tpn;
  int c = (threadIdx.x % tpn) * 2;
  const unsigned short* base = feat + (size_t)node * D + c;
  ushort2 s = *(const ushort2*)base;
  float a0 = b2f(s.x), a1 = b2f(s.y);
  int beg = rowptr[node], end = rowptr[node + 1];
  for (int i = beg; i < end; ++i) {
    int src = ssrc[i];
    ushort2 v = *(const ushort2*)(feat + (size_t)src * D + c);
    a0 += b2f(v.x); a1 += b2f(v.y);
  }
  ushort2 o; o.x = f2b(a0); o.y = f2b(a1);
  *(ushort2*)(out + (size_t)node * D + c) = o;
}

// ---- C(M x 256) = relu(A(M x K) @ W + b), bf16 out.
__global__ void gemm_relu(const unsigned short* __restrict__ A,
                          const unsigned short* __restrict__ Wp,
                          const unsigned short* __restrict__ Wb, int bias_row,
                          unsigned short* __restrict__ C, int K) {
  const int row0 = blockIdx.x << 4;
  const int lane = threadIdx.x & 63;
  const int wave = threadIdx.x >> 6;
  const int m = lane & 15;
  const int q = lane >> 4;
  f32x4 acc[4];
#pragma unroll
  for (int t = 0; t < 4; ++t) acc[t] = (f32x4){0.f, 0.f, 0.f, 0.f};

  const unsigned short* arow = A + (size_t)(row0 + m) * K + (q << 3);
  const int nb = (wave << 6) + m;
  const int kblocks = K >> 5;
  for (int kb = 0; kb < kblocks; ++kb) {
    bf16x8 af = *(const bf16x8*)(arow + (kb << 5));
    const unsigned short* wp = Wp + (((size_t)(kb << 8) + nb) * 4 + q) * 8;
    bf16x8 b0 = *(const bf16x8*)(wp);
    bf16x8 b1 = *(const bf16x8*)(wp + 512);
    bf16x8 b2 = *(const bf16x8*)(wp + 1024);
    bf16x8 b3 = *(const bf16x8*)(wp + 1536);
    acc[0] = __builtin_amdgcn_mfma_f32_16x16x32_bf16(af, b0, acc[0], 0, 0, 0);
    acc[1] = __builtin_amdgcn_mfma_f32_16x16x32_bf16(af, b1, acc[1], 0, 0, 0);
    acc[2] = __builtin_amdgcn_mfma_f32_16x16x32_bf16(af, b2, acc[2], 0, 0, 0);
    acc[3] = __builtin_amdgcn_mfma_f32_16x16x32_bf16(af, b3, acc[3], 0, 0, 0);
  }
#pragma unroll
  for (int t = 0; t < 4; ++t) {
    int n = (wave << 6) + (t << 4) + m;
    float bv = b2f(Wb[bias_row * 256 + n]);
#pragma unroll
    for (int i = 0; i < 4; ++i) {
      int r = row0 + (q << 2) + i;
      float v = fmaxf(acc[t][i] + bv, 0.f);
      C[(size_t)r * 256 + n] = f2b(v);
    }
  }
}

// ---- mean pool: batch sorted; binary search bounds; dtype-aware
__device__ __forceinline__ int lower_bound(const int* a, int n, int v, int is64) {
  int lo = 0, hi = n;
  while (lo < hi) {
    int mid = (lo + hi) >> 1;
    int bv = is64 ? a[2 * mid] : a[mid];
    if (bv < v) lo = mid + 1; else hi = mid;
  }
  return lo;
}

__global__ void pool_kernel(const unsigned short* __restrict__ h2,
                            const int* __restrict__ batch,
                            void* __restrict__ out,
                            const int* __restrict__ flags) {
  __shared__ int sh[2];
  int g = blockIdx.x;
  int is64 = flags[1];
  if (threadIdx.x == 0) sh[0] = lower_bound(batch, N_NODES, g, is64);
  if (threadIdx.x == 1) sh[1] = lower_bound(batch, N_NODES, g + 1, is64);
  __syncthreads();
  int s = sh[0], e = sh[1];
  int c = threadIdx.x;
  float acc = 0.f;
  for (int r = s; r < e; ++r) acc += b2f(h2[(size_t)r * 256 + c]);
  float res = acc / fmaxf((float)(e - s), 1.0f);
  if (flags[0]) ((unsigned short*)out)[(size_t)g * 256 + c] = f2b(res);
  else          ((float*)out)[(size_t)g * 256 + c] = res;
}

extern "C" void kernel_launch(void* const* d_in, const int* in_sizes, int n_in,
                              void* d_out, int out_size, void* d_ws, size_t ws_size,
                              hipStream_t stream) {
  const void* x    = d_in[0];
  const int*  ei   = (const int*)d_in[1];
  const int*  batch= (const int*)d_in[2];

  char* ws = (char*)d_ws;
  int*            flags = (int*)(ws + OFF_FLAGS);
  unsigned short* Wb    = (unsigned short*)(ws + OFF_WB);
  unsigned short* Wp0   = (unsigned short*)(ws + OFF_WP0);
  unsigned short* Wp1   = (unsigned short*)(ws + OFF_WP1);
  unsigned short* Wp2   = (unsigned short*)(ws + OFF_WP2);
  unsigned short* Wp3   = (unsigned short*)(ws + OFF_WP3);
  int*            cnts  = (int*)(ws + OFF_CNT);
  int*            rowp  = (int*)(ws + OFF_ROWPTR);
  int*            curs  = (int*)(ws + OFF_CURSOR);
  unsigned short* ssrc  = (unsigned short*)(ws + OFF_SSRC);
  unsigned short* A     = (unsigned short*)(ws + OFF_A);
  unsigned short* B     = (unsigned short*)(ws + OFF_B);
  unsigned short* C     = (unsigned short*)(ws + OFF_C);

  detect_kernel<<<1, 256, 0, stream>>>((const unsigned int*)x, (const unsigned int*)ei, flags);

  // weights + CSR build (independent of features)
  pack_w<<<16, 256, 0, stream>>>(d_in[3], Wp0, 128, flags);
  pack_w<<<32, 256, 0, stream>>>(d_in[5], Wp1, 256, flags);
  pack_w<<<32, 256, 0, stream>>>(d_in[7], Wp2, 256, flags);
  pack_w<<<32, 256, 0, stream>>>(d_in[9], Wp3, 256, flags);
  pack_bias<<<4, 256, 0, stream>>>(d_in[4], d_in[6], d_in[8], d_in[10], Wb, flags);

  zero_counts<<<196, 256, 0, stream>>>(cnts);
  hist_kernel<<<3125, 256, 0, stream>>>(ei, cnts, flags);
  scan_kernel<<<1, 1024, 0, stream>>>(cnts, rowp, curs);
  fill_kernel<<<3125, 256, 0, stream>>>(ei, curs, ssrc, flags);

  // layer 1
  conv_to_bf16<<<25000, 256, 0, stream>>>(x, A, 6400000, flags);
  gather_kernel<<<12500, 256, 0, stream>>>(A, rowp, ssrc, B, 128);
  gemm_relu<<<3125, 256, 0, stream>>>(B, Wp0, Wb, 0, C, 128);   // t  -> C
  gemm_relu<<<3125, 256, 0, stream>>>(C, Wp1, Wb, 1, B, 256);   // h1 -> B

  // layer 2
  gather_kernel<<<25000, 256, 0, stream>>>(B, rowp, ssrc, C, 256);
  gemm_relu<<<3125, 256, 0, stream>>>(C, Wp2, Wb, 2, B, 256);   // t2 -> B
  gemm_relu<<<3125, 256, 0, stream>>>(B, Wp3, Wb, 3, C, 256);   // h2 -> C

  // pool
  pool_kernel<<<N_GRAPHS, 256, 0, stream>>>(C, batch, d_out, flags);
}

// Round 4
// 600.232 us; speedup vs baseline: 7.5003x; 1.4660x over previous
//
#include <hip/hip_runtime.h>

// ---------------------------------------------------------------------------
// GIN (2 layers) + global mean pool, MI355X (gfx950).
// R4: parallelize mean-pool (213us -> ~20us; 64 blocks was 2.5% occupancy),
// widen gather loads to ushort4 + 2-edge unroll, fuse zero-inits.
//
// ws: [flags][Wb][Wp0..3][counts][rowptr][cursor][ssrc u16][A][B][C][pool32]
// ---------------------------------------------------------------------------

typedef __bf16 bf16x8 __attribute__((ext_vector_type(8)));
typedef float f32x4 __attribute__((ext_vector_type(4)));

#define N_NODES 50000
#define N_EDGES 800000
#define N_GRAPHS 64
#define POOL_ROWS 128

#define OFF_FLAGS  0ull
#define OFF_WB     64ull
#define OFF_WP0    4096ull
#define OFF_WP1    (OFF_WP0 + 65536ull)
#define OFF_WP2    (OFF_WP1 + 131072ull)
#define OFF_WP3    (OFF_WP2 + 131072ull)
#define OFF_CNT    462848ull
#define OFF_ROWPTR 662864ull
#define OFF_CURSOR 862880ull
#define OFF_SSRC   1062912ull
#define OFF_A      2662912ull               // 12.8 MB
#define OFF_B      15462912ull              // 25.6 MB
#define OFF_C      41062912ull              // 25.6 MB
#define OFF_POOL32 66662912ull              // 64 KB   (end ~66.73 MB)

__device__ __forceinline__ float b2f(unsigned short u) {
  union { unsigned int i; float f; } v; v.i = ((unsigned int)u) << 16; return v.f;
}
__device__ __forceinline__ unsigned short f2b(float f) {
  union { unsigned int i; float f; } v; v.f = f;
  unsigned int r = v.i + 0x7fffu + ((v.i >> 16) & 1u);
  return (unsigned short)(r >> 16);
}

// ---- dtype detection: flags[0]=floats-are-bf16, flags[1]=ints-are-64bit
__global__ void detect_kernel(const unsigned int* __restrict__ xw,
                              const unsigned int* __restrict__ eiw,
                              int* __restrict__ flags) {
  __shared__ int s_f[256], s_i[256];
  int t = threadIdx.x;
  int fh = 0, iz = 0;
  for (int i = t; i < 1024; i += 256) {
    unsigned int e = (xw[i] >> 7) & 0xFFu;
    fh += (e >= 115u && e <= 130u) ? 1 : 0;
    iz += (eiw[2 * i + 1] == 0u) ? 1 : 0;
  }
  s_f[t] = fh; s_i[t] = iz;
  __syncthreads();
  for (int s = 128; s > 0; s >>= 1) {
    if (t < s) { s_f[t] += s_f[t + s]; s_i[t] += s_i[t + s]; }
    __syncthreads();
  }
  if (t == 0) { flags[0] = s_f[0] > 512 ? 1 : 0; flags[1] = s_i[0] > 512 ? 1 : 0; }
}

__global__ void conv_to_bf16(const void* __restrict__ raw,
                             unsigned short* __restrict__ outb, int n,
                             const int* __restrict__ flags) {
  int i = blockIdx.x * blockDim.x + threadIdx.x;
  if (i >= n) return;
  outb[i] = flags[0] ? ((const unsigned short*)raw)[i]
                     : f2b(((const float*)raw)[i]);
}

// ---- pack W (K x 256 row-major) into MFMA b-frag order, dtype-aware read.
__global__ void pack_w(const void* __restrict__ W,
                       unsigned short* __restrict__ Wp, int K,
                       const int* __restrict__ flags) {
  int tid = blockIdx.x * blockDim.x + threadIdx.x;
  int total = (K >> 5) << 10;
  if (tid >= total) return;
  int q = tid & 3;
  int n = (tid >> 2) & 255;
  int kb = tid >> 10;
  int krow = (kb << 5) + (q << 3);
  int isb = flags[0];
  unsigned short* o = Wp + (size_t)tid * 8;
#pragma unroll
  for (int j = 0; j < 8; ++j) {
    size_t idx = (size_t)(krow + j) * 256 + n;
    o[j] = isb ? ((const unsigned short*)W)[idx] : f2b(((const float*)W)[idx]);
  }
}

__global__ void pack_bias(const void* b0, const void* b1, const void* b2, const void* b3,
                          unsigned short* __restrict__ Wb,
                          const int* __restrict__ flags) {
  int t = blockIdx.x * blockDim.x + threadIdx.x;
  if (t >= 1024) return;
  const void* p = (t < 256) ? b0 : (t < 512) ? b1 : (t < 768) ? b2 : b3;
  int n = t & 255;
  Wb[t] = flags[0] ? ((const unsigned short*)p)[n] : f2b(((const float*)p)[n]);
}

// ---- zero counts + pool accumulator in one pass
__global__ void zero_ws(int* __restrict__ counts, float* __restrict__ pool32) {
  int i = blockIdx.x * blockDim.x + threadIdx.x;
  if (i < N_NODES) counts[i] = 0;
  if (i < N_GRAPHS * 256) pool32[i] = 0.f;
}

__global__ void hist_kernel(const int* __restrict__ ei, int* __restrict__ counts,
                            const int* __restrict__ flags) {
  int e = blockIdx.x * blockDim.x + threadIdx.x;
  if (e >= N_EDGES) return;
  int is64 = flags[1];
  int dst = is64 ? ei[2 * (N_EDGES + e)] : ei[N_EDGES + e];
  atomicAdd(&counts[dst], 1);
}

// single block, 1024 threads: exclusive scan of counts -> rowptr + cursor
__global__ void scan_kernel(const int* __restrict__ counts,
                            int* __restrict__ rowptr, int* __restrict__ cursor) {
  __shared__ int sdata[1024];
  const int CH = 49;
  int t = threadIdx.x;
  int lo = t * CH;
  int sum = 0;
  for (int i = lo; i < lo + CH && i < N_NODES; ++i) sum += counts[i];
  sdata[t] = sum;
  __syncthreads();
  for (int off = 1; off < 1024; off <<= 1) {
    int v = (t >= off) ? sdata[t - off] : 0;
    __syncthreads();
    sdata[t] += v;
    __syncthreads();
  }
  int run = sdata[t] - sum;
  for (int i = lo; i < lo + CH && i < N_NODES; ++i) {
    rowptr[i] = run; cursor[i] = run;
    run += counts[i];
  }
  if (t == 1023) rowptr[N_NODES] = sdata[1023];
}

__global__ void fill_kernel(const int* __restrict__ ei, int* __restrict__ cursor,
                            unsigned short* __restrict__ ssrc,
                            const int* __restrict__ flags) {
  int e = blockIdx.x * blockDim.x + threadIdx.x;
  if (e >= N_EDGES) return;
  int is64 = flags[1];
  int src = is64 ? ei[2 * e] : ei[e];
  int dst = is64 ? ei[2 * (N_EDGES + e)] : ei[N_EDGES + e];
  int pos = atomicAdd(&cursor[dst], 1);
  ssrc[pos] = (unsigned short)src;
}

// ---- gather-reduce: out[n][:] = feat[n][:] + sum_{src in N(n)} feat[src][:]
// thread = (node, 4-col group); ushort4 loads, 2-edge unroll.
__global__ void gather_kernel(const unsigned short* __restrict__ feat,
                              const int* __restrict__ rowptr,
                              const unsigned short* __restrict__ ssrc,
                              unsigned short* __restrict__ out, int D) {
  int tpn = D >> 2;
  int npb = 256 / tpn;
  int node = blockIdx.x * npb + threadIdx.x / tpn;
  int c = (threadIdx.x % tpn) * 4;
  const unsigned short* base = feat + (size_t)node * D + c;
  ushort4 s = *(const ushort4*)base;
  float a0 = b2f(s.x), a1 = b2f(s.y), a2 = b2f(s.z), a3 = b2f(s.w);
  int beg = rowptr[node], end = rowptr[node + 1];
  int i = beg;
  for (; i + 1 < end; i += 2) {
    int s0 = ssrc[i], s1 = ssrc[i + 1];
    ushort4 v0 = *(const ushort4*)(feat + (size_t)s0 * D + c);
    ushort4 v1 = *(const ushort4*)(feat + (size_t)s1 * D + c);
    a0 += b2f(v0.x); a1 += b2f(v0.y); a2 += b2f(v0.z); a3 += b2f(v0.w);
    a0 += b2f(v1.x); a1 += b2f(v1.y); a2 += b2f(v1.z); a3 += b2f(v1.w);
  }
  if (i < end) {
    ushort4 v = *(const ushort4*)(feat + (size_t)ssrc[i] * D + c);
    a0 += b2f(v.x); a1 += b2f(v.y); a2 += b2f(v.z); a3 += b2f(v.w);
  }
  ushort4 o; o.x = f2b(a0); o.y = f2b(a1); o.z = f2b(a2); o.w = f2b(a3);
  *(ushort4*)(out + (size_t)node * D + c) = o;
}

// ---- C(M x 256) = relu(A(M x K) @ W + b), bf16 out.
__global__ void gemm_relu(const unsigned short* __restrict__ A,
                          const unsigned short* __restrict__ Wp,
                          const unsigned short* __restrict__ Wb, int bias_row,
                          unsigned short* __restrict__ C, int K) {
  const int row0 = blockIdx.x << 4;
  const int lane = threadIdx.x & 63;
  const int wave = threadIdx.x >> 6;
  const int m = lane & 15;
  const int q = lane >> 4;
  f32x4 acc[4];
#pragma unroll
  for (int t = 0; t < 4; ++t) acc[t] = (f32x4){0.f, 0.f, 0.f, 0.f};

  const unsigned short* arow = A + (size_t)(row0 + m) * K + (q << 3);
  const int nb = (wave << 6) + m;
  const int kblocks = K >> 5;
  for (int kb = 0; kb < kblocks; ++kb) {
    bf16x8 af = *(const bf16x8*)(arow + (kb << 5));
    const unsigned short* wp = Wp + (((size_t)(kb << 8) + nb) * 4 + q) * 8;
    bf16x8 b0 = *(const bf16x8*)(wp);
    bf16x8 b1 = *(const bf16x8*)(wp + 512);
    bf16x8 b2 = *(const bf16x8*)(wp + 1024);
    bf16x8 b3 = *(const bf16x8*)(wp + 1536);
    acc[0] = __builtin_amdgcn_mfma_f32_16x16x32_bf16(af, b0, acc[0], 0, 0, 0);
    acc[1] = __builtin_amdgcn_mfma_f32_16x16x32_bf16(af, b1, acc[1], 0, 0, 0);
    acc[2] = __builtin_amdgcn_mfma_f32_16x16x32_bf16(af, b2, acc[2], 0, 0, 0);
    acc[3] = __builtin_amdgcn_mfma_f32_16x16x32_bf16(af, b3, acc[3], 0, 0, 0);
  }
#pragma unroll
  for (int t = 0; t < 4; ++t) {
    int n = (wave << 6) + (t << 4) + m;
    float bv = b2f(Wb[bias_row * 256 + n]);
#pragma unroll
    for (int i = 0; i < 4; ++i) {
      int r = row0 + (q << 2) + i;
      float v = fmaxf(acc[t][i] + bv, 0.f);
      C[(size_t)r * 256 + n] = f2b(v);
    }
  }
}

// ---- parallel mean pool: stage 1 partials + atomics, stage 2 finalize
__global__ void pool_partial(const unsigned short* __restrict__ h2,
                             const int* __restrict__ batch,
                             float* __restrict__ pool32,
                             const int* __restrict__ flags) {
  __shared__ int sg[POOL_ROWS];
  int r0 = blockIdx.x * POOL_ROWS;
  int nr = N_NODES - r0; if (nr > POOL_ROWS) nr = POOL_ROWS;
  int is64 = flags[1];
  for (int i = threadIdx.x; i < nr; i += 256)
    sg[i] = is64 ? batch[2 * (r0 + i)] : batch[r0 + i];
  __syncthreads();
  int c = threadIdx.x;
  float acc = 0.f;
  int cur = sg[0];
  for (int i = 0; i < nr; ++i) {
    int g = sg[i];
    if (g != cur) {
      unsafeAtomicAdd(&pool32[cur * 256 + c], acc);
      acc = 0.f; cur = g;
    }
    acc += b2f(h2[(size_t)(r0 + i) * 256 + c]);
  }
  unsafeAtomicAdd(&pool32[cur * 256 + c], acc);
}

__device__ __forceinline__ int lower_bound(const int* a, int n, int v, int is64) {
  int lo = 0, hi = n;
  while (lo < hi) {
    int mid = (lo + hi) >> 1;
    int bv = is64 ? a[2 * mid] : a[mid];
    if (bv < v) lo = mid + 1; else hi = mid;
  }
  return lo;
}

__global__ void pool_final(const float* __restrict__ pool32,
                           const int* __restrict__ batch,
                           void* __restrict__ out,
                           const int* __restrict__ flags) {
  __shared__ int sh[2];
  int g = blockIdx.x;
  int is64 = flags[1];
  if (threadIdx.x == 0) sh[0] = lower_bound(batch, N_NODES, g, is64);
  if (threadIdx.x == 1) sh[1] = lower_bound(batch, N_NODES, g + 1, is64);
  __syncthreads();
  int c = threadIdx.x;
  float res = pool32[g * 256 + c] / fmaxf((float)(sh[1] - sh[0]), 1.0f);
  if (flags[0]) ((unsigned short*)out)[(size_t)g * 256 + c] = f2b(res);
  else          ((float*)out)[(size_t)g * 256 + c] = res;
}

extern "C" void kernel_launch(void* const* d_in, const int* in_sizes, int n_in,
                              void* d_out, int out_size, void* d_ws, size_t ws_size,
                              hipStream_t stream) {
  const void* x    = d_in[0];
  const int*  ei   = (const int*)d_in[1];
  const int*  batch= (const int*)d_in[2];

  char* ws = (char*)d_ws;
  int*            flags = (int*)(ws + OFF_FLAGS);
  unsigned short* Wb    = (unsigned short*)(ws + OFF_WB);
  unsigned short* Wp0   = (unsigned short*)(ws + OFF_WP0);
  unsigned short* Wp1   = (unsigned short*)(ws + OFF_WP1);
  unsigned short* Wp2   = (unsigned short*)(ws + OFF_WP2);
  unsigned short* Wp3   = (unsigned short*)(ws + OFF_WP3);
  int*            cnts  = (int*)(ws + OFF_CNT);
  int*            rowp  = (int*)(ws + OFF_ROWPTR);
  int*            curs  = (int*)(ws + OFF_CURSOR);
  unsigned short* ssrc  = (unsigned short*)(ws + OFF_SSRC);
  unsigned short* A     = (unsigned short*)(ws + OFF_A);
  unsigned short* B     = (unsigned short*)(ws + OFF_B);
  unsigned short* C     = (unsigned short*)(ws + OFF_C);
  float*          pool32= (float*)(ws + OFF_POOL32);

  detect_kernel<<<1, 256, 0, stream>>>((const unsigned int*)x, (const unsigned int*)ei, flags);

  pack_w<<<16, 256, 0, stream>>>(d_in[3], Wp0, 128, flags);
  pack_w<<<32, 256, 0, stream>>>(d_in[5], Wp1, 256, flags);
  pack_w<<<32, 256, 0, stream>>>(d_in[7], Wp2, 256, flags);
  pack_w<<<32, 256, 0, stream>>>(d_in[9], Wp3, 256, flags);
  pack_bias<<<4, 256, 0, stream>>>(d_in[4], d_in[6], d_in[8], d_in[10], Wb, flags);

  zero_ws<<<196, 256, 0, stream>>>(cnts, pool32);
  hist_kernel<<<3125, 256, 0, stream>>>(ei, cnts, flags);
  scan_kernel<<<1, 1024, 0, stream>>>(cnts, rowp, curs);
  fill_kernel<<<3125, 256, 0, stream>>>(ei, curs, ssrc, flags);

  // layer 1
  conv_to_bf16<<<25000, 256, 0, stream>>>(x, A, 6400000, flags);
  gather_kernel<<<6250, 256, 0, stream>>>(A, rowp, ssrc, B, 128);
  gemm_relu<<<3125, 256, 0, stream>>>(B, Wp0, Wb, 0, C, 128);   // t  -> C
  gemm_relu<<<3125, 256, 0, stream>>>(C, Wp1, Wb, 1, B, 256);   // h1 -> B

  // layer 2
  gather_kernel<<<12500, 256, 0, stream>>>(B, rowp, ssrc, C, 256);
  gemm_relu<<<3125, 256, 0, stream>>>(C, Wp2, Wb, 2, B, 256);   // t2 -> B
  gemm_relu<<<3125, 256, 0, stream>>>(B, Wp3, Wb, 3, C, 256);   // h2 -> C

  // pool
  pool_partial<<<(N_NODES + POOL_ROWS - 1) / POOL_ROWS, 256, 0, stream>>>(C, batch, pool32, flags);
  pool_final<<<N_GRAPHS, 256, 0, stream>>>(pool32, batch, d_out, flags);
}

// Round 5
// 483.730 us; speedup vs baseline: 9.3067x; 1.2408x over previous
//
#include <hip/hip_runtime.h>

// ---------------------------------------------------------------------------
// GIN (2 layers) + global mean pool, MI355X (gfx950).
// R5: multi-block CSR scan (single-block scan was 111us @ 0.14% occupancy),
// vectorized input conversion (16B/thread).
//
// ws: [flags][Wb][Wp0..3][counts][rowptr][cursor][ssrc u16][A][B][C][pool32][bsum][boff]
// ---------------------------------------------------------------------------

typedef __bf16 bf16x8 __attribute__((ext_vector_type(8)));
typedef float f32x4 __attribute__((ext_vector_type(4)));

#define N_NODES 50000
#define N_EDGES 800000
#define N_GRAPHS 64
#define POOL_ROWS 128
#define SCAN_BLOCKS 196   // ceil(50000/256)

#define OFF_FLAGS  0ull
#define OFF_WB     64ull
#define OFF_WP0    4096ull
#define OFF_WP1    (OFF_WP0 + 65536ull)
#define OFF_WP2    (OFF_WP1 + 131072ull)
#define OFF_WP3    (OFF_WP2 + 131072ull)
#define OFF_CNT    462848ull
#define OFF_ROWPTR 662864ull
#define OFF_CURSOR 862880ull
#define OFF_SSRC   1062912ull
#define OFF_A      2662912ull               // 12.8 MB
#define OFF_B      15462912ull              // 25.6 MB
#define OFF_C      41062912ull              // 25.6 MB
#define OFF_POOL32 66662912ull              // 64 KB
#define OFF_BSUM   66728448ull              // 1 KB
#define OFF_BOFF   66729472ull              // 1 KB (end ~66.73 MB)

__device__ __forceinline__ float b2f(unsigned short u) {
  union { unsigned int i; float f; } v; v.i = ((unsigned int)u) << 16; return v.f;
}
__device__ __forceinline__ unsigned short f2b(float f) {
  union { unsigned int i; float f; } v; v.f = f;
  unsigned int r = v.i + 0x7fffu + ((v.i >> 16) & 1u);
  return (unsigned short)(r >> 16);
}

// ---- dtype detection: flags[0]=floats-are-bf16, flags[1]=ints-are-64bit
__global__ void detect_kernel(const unsigned int* __restrict__ xw,
                              const unsigned int* __restrict__ eiw,
                              int* __restrict__ flags) {
  __shared__ int s_f[256], s_i[256];
  int t = threadIdx.x;
  int fh = 0, iz = 0;
  for (int i = t; i < 1024; i += 256) {
    unsigned int e = (xw[i] >> 7) & 0xFFu;
    fh += (e >= 115u && e <= 130u) ? 1 : 0;
    iz += (eiw[2 * i + 1] == 0u) ? 1 : 0;
  }
  s_f[t] = fh; s_i[t] = iz;
  __syncthreads();
  for (int s = 128; s > 0; s >>= 1) {
    if (t < s) { s_f[t] += s_f[t + s]; s_i[t] += s_i[t + s]; }
    __syncthreads();
  }
  if (t == 0) { flags[0] = s_f[0] > 512 ? 1 : 0; flags[1] = s_i[0] > 512 ? 1 : 0; }
}

// ---- vectorized raw float input -> canonical bf16; thread = 8 elems
__global__ void conv_to_bf16(const void* __restrict__ raw,
                             unsigned short* __restrict__ outb, int n8,
                             const int* __restrict__ flags) {
  int i = blockIdx.x * blockDim.x + threadIdx.x;
  if (i >= n8) return;
  if (flags[0]) {
    ((uint4*)outb)[i] = ((const uint4*)raw)[i];
  } else {
    const float4* f = (const float4*)raw;
    float4 a = f[2 * i], b = f[2 * i + 1];
    ushort4 o0; o0.x = f2b(a.x); o0.y = f2b(a.y); o0.z = f2b(a.z); o0.w = f2b(a.w);
    ushort4 o1; o1.x = f2b(b.x); o1.y = f2b(b.y); o1.z = f2b(b.z); o1.w = f2b(b.w);
    ((ushort4*)outb)[2 * i] = o0;
    ((ushort4*)outb)[2 * i + 1] = o1;
  }
}

// ---- pack W (K x 256 row-major) into MFMA b-frag order, dtype-aware read.
__global__ void pack_w(const void* __restrict__ W,
                       unsigned short* __restrict__ Wp, int K,
                       const int* __restrict__ flags) {
  int tid = blockIdx.x * blockDim.x + threadIdx.x;
  int total = (K >> 5) << 10;
  if (tid >= total) return;
  int q = tid & 3;
  int n = (tid >> 2) & 255;
  int kb = tid >> 10;
  int krow = (kb << 5) + (q << 3);
  int isb = flags[0];
  unsigned short* o = Wp + (size_t)tid * 8;
#pragma unroll
  for (int j = 0; j < 8; ++j) {
    size_t idx = (size_t)(krow + j) * 256 + n;
    o[j] = isb ? ((const unsigned short*)W)[idx] : f2b(((const float*)W)[idx]);
  }
}

__global__ void pack_bias(const void* b0, const void* b1, const void* b2, const void* b3,
                          unsigned short* __restrict__ Wb,
                          const int* __restrict__ flags) {
  int t = blockIdx.x * blockDim.x + threadIdx.x;
  if (t >= 1024) return;
  const void* p = (t < 256) ? b0 : (t < 512) ? b1 : (t < 768) ? b2 : b3;
  int n = t & 255;
  Wb[t] = flags[0] ? ((const unsigned short*)p)[n] : f2b(((const float*)p)[n]);
}

// ---- zero counts + pool accumulator
__global__ void zero_ws(int* __restrict__ counts, float* __restrict__ pool32) {
  int i = blockIdx.x * blockDim.x + threadIdx.x;
  if (i < N_NODES) counts[i] = 0;
  if (i < N_GRAPHS * 256) pool32[i] = 0.f;
}

__global__ void hist_kernel(const int* __restrict__ ei, int* __restrict__ counts,
                            const int* __restrict__ flags) {
  int e = blockIdx.x * blockDim.x + threadIdx.x;
  if (e >= N_EDGES) return;
  int is64 = flags[1];
  int dst = is64 ? ei[2 * (N_EDGES + e)] : ei[N_EDGES + e];
  atomicAdd(&counts[dst], 1);
}

// ---- 3-stage scan ---------------------------------------------------------
// Stage 1: per-256-chunk LDS scan; local exclusive -> rowptr, chunk sum -> bsum
__global__ void scan_blocks(const int* __restrict__ counts,
                            int* __restrict__ rowptr, int* __restrict__ bsum) {
  __shared__ int sd[256];
  int t = threadIdx.x;
  int i = blockIdx.x * 256 + t;
  int v = (i < N_NODES) ? counts[i] : 0;
  sd[t] = v;
  __syncthreads();
  for (int off = 1; off < 256; off <<= 1) {
    int u = (t >= off) ? sd[t - off] : 0;
    __syncthreads();
    sd[t] += u;
    __syncthreads();
  }
  if (i < N_NODES) rowptr[i] = sd[t] - v;
  if (t == 255) bsum[blockIdx.x] = sd[255];
}

// Stage 2: one block scans the SCAN_BLOCKS sums -> exclusive offsets
__global__ void scan_sums(const int* __restrict__ bsum, int* __restrict__ boff) {
  __shared__ int sd[256];
  int t = threadIdx.x;
  int v = (t < SCAN_BLOCKS) ? bsum[t] : 0;
  sd[t] = v;
  __syncthreads();
  for (int off = 1; off < 256; off <<= 1) {
    int u = (t >= off) ? sd[t - off] : 0;
    __syncthreads();
    sd[t] += u;
    __syncthreads();
  }
  if (t < SCAN_BLOCKS) boff[t] = sd[t] - v;
}

// Stage 3: add block offset in place; mirror into cursor; cap rowptr.
__global__ void scan_add(int* __restrict__ rowptr, int* __restrict__ cursor,
                         const int* __restrict__ boff) {
  int i = blockIdx.x * 256 + threadIdx.x;
  if (i < N_NODES) {
    int v = rowptr[i] + boff[blockIdx.x];
    rowptr[i] = v;
    cursor[i] = v;
  }
  if (i == 0) rowptr[N_NODES] = N_EDGES;
}

__global__ void fill_kernel(const int* __restrict__ ei, int* __restrict__ cursor,
                            unsigned short* __restrict__ ssrc,
                            const int* __restrict__ flags) {
  int e = blockIdx.x * blockDim.x + threadIdx.x;
  if (e >= N_EDGES) return;
  int is64 = flags[1];
  int src = is64 ? ei[2 * e] : ei[e];
  int dst = is64 ? ei[2 * (N_EDGES + e)] : ei[N_EDGES + e];
  int pos = atomicAdd(&cursor[dst], 1);
  ssrc[pos] = (unsigned short)src;
}

// ---- gather-reduce: out[n][:] = feat[n][:] + sum_{src in N(n)} feat[src][:]
__global__ void gather_kernel(const unsigned short* __restrict__ feat,
                              const int* __restrict__ rowptr,
                              const unsigned short* __restrict__ ssrc,
                              unsigned short* __restrict__ out, int D) {
  int tpn = D >> 2;
  int npb = 256 / tpn;
  int node = blockIdx.x * npb + threadIdx.x / tpn;
  int c = (threadIdx.x % tpn) * 4;
  const unsigned short* base = feat + (size_t)node * D + c;
  ushort4 s = *(const ushort4*)base;
  float a0 = b2f(s.x), a1 = b2f(s.y), a2 = b2f(s.z), a3 = b2f(s.w);
  int beg = rowptr[node], end = rowptr[node + 1];
  int i = beg;
  for (; i + 1 < end; i += 2) {
    int s0 = ssrc[i], s1 = ssrc[i + 1];
    ushort4 v0 = *(const ushort4*)(feat + (size_t)s0 * D + c);
    ushort4 v1 = *(const ushort4*)(feat + (size_t)s1 * D + c);
    a0 += b2f(v0.x); a1 += b2f(v0.y); a2 += b2f(v0.z); a3 += b2f(v0.w);
    a0 += b2f(v1.x); a1 += b2f(v1.y); a2 += b2f(v1.z); a3 += b2f(v1.w);
  }
  if (i < end) {
    ushort4 v = *(const ushort4*)(feat + (size_t)ssrc[i] * D + c);
    a0 += b2f(v.x); a1 += b2f(v.y); a2 += b2f(v.z); a3 += b2f(v.w);
  }
  ushort4 o; o.x = f2b(a0); o.y = f2b(a1); o.z = f2b(a2); o.w = f2b(a3);
  *(ushort4*)(out + (size_t)node * D + c) = o;
}

// ---- C(M x 256) = relu(A(M x K) @ W + b), bf16 out.
__global__ void gemm_relu(const unsigned short* __restrict__ A,
                          const unsigned short* __restrict__ Wp,
                          const unsigned short* __restrict__ Wb, int bias_row,
                          unsigned short* __restrict__ C, int K) {
  const int row0 = blockIdx.x << 4;
  const int lane = threadIdx.x & 63;
  const int wave = threadIdx.x >> 6;
  const int m = lane & 15;
  const int q = lane >> 4;
  f32x4 acc[4];
#pragma unroll
  for (int t = 0; t < 4; ++t) acc[t] = (f32x4){0.f, 0.f, 0.f, 0.f};

  const unsigned short* arow = A + (size_t)(row0 + m) * K + (q << 3);
  const int nb = (wave << 6) + m;
  const int kblocks = K >> 5;
  for (int kb = 0; kb < kblocks; ++kb) {
    bf16x8 af = *(const bf16x8*)(arow + (kb << 5));
    const unsigned short* wp = Wp + (((size_t)(kb << 8) + nb) * 4 + q) * 8;
    bf16x8 b0 = *(const bf16x8*)(wp);
    bf16x8 b1 = *(const bf16x8*)(wp + 512);
    bf16x8 b2 = *(const bf16x8*)(wp + 1024);
    bf16x8 b3 = *(const bf16x8*)(wp + 1536);
    acc[0] = __builtin_amdgcn_mfma_f32_16x16x32_bf16(af, b0, acc[0], 0, 0, 0);
    acc[1] = __builtin_amdgcn_mfma_f32_16x16x32_bf16(af, b1, acc[1], 0, 0, 0);
    acc[2] = __builtin_amdgcn_mfma_f32_16x16x32_bf16(af, b2, acc[2], 0, 0, 0);
    acc[3] = __builtin_amdgcn_mfma_f32_16x16x32_bf16(af, b3, acc[3], 0, 0, 0);
  }
#pragma unroll
  for (int t = 0; t < 4; ++t) {
    int n = (wave << 6) + (t << 4) + m;
    float bv = b2f(Wb[bias_row * 256 + n]);
#pragma unroll
    for (int i = 0; i < 4; ++i) {
      int r = row0 + (q << 2) + i;
      float v = fmaxf(acc[t][i] + bv, 0.f);
      C[(size_t)r * 256 + n] = f2b(v);
    }
  }
}

// ---- parallel mean pool
__global__ void pool_partial(const unsigned short* __restrict__ h2,
                             const int* __restrict__ batch,
                             float* __restrict__ pool32,
                             const int* __restrict__ flags) {
  __shared__ int sg[POOL_ROWS];
  int r0 = blockIdx.x * POOL_ROWS;
  int nr = N_NODES - r0; if (nr > POOL_ROWS) nr = POOL_ROWS;
  int is64 = flags[1];
  for (int i = threadIdx.x; i < nr; i += 256)
    sg[i] = is64 ? batch[2 * (r0 + i)] : batch[r0 + i];
  __syncthreads();
  int c = threadIdx.x;
  float acc = 0.f;
  int cur = sg[0];
  for (int i = 0; i < nr; ++i) {
    int g = sg[i];
    if (g != cur) {
      unsafeAtomicAdd(&pool32[cur * 256 + c], acc);
      acc = 0.f; cur = g;
    }
    acc += b2f(h2[(size_t)(r0 + i) * 256 + c]);
  }
  unsafeAtomicAdd(&pool32[cur * 256 + c], acc);
}

__device__ __forceinline__ int lower_bound(const int* a, int n, int v, int is64) {
  int lo = 0, hi = n;
  while (lo < hi) {
    int mid = (lo + hi) >> 1;
    int bv = is64 ? a[2 * mid] : a[mid];
    if (bv < v) lo = mid + 1; else hi = mid;
  }
  return lo;
}

__global__ void pool_final(const float* __restrict__ pool32,
                           const int* __restrict__ batch,
                           void* __restrict__ out,
                           const int* __restrict__ flags) {
  __shared__ int sh[2];
  int g = blockIdx.x;
  int is64 = flags[1];
  if (threadIdx.x == 0) sh[0] = lower_bound(batch, N_NODES, g, is64);
  if (threadIdx.x == 1) sh[1] = lower_bound(batch, N_NODES, g + 1, is64);
  __syncthreads();
  int c = threadIdx.x;
  float res = pool32[g * 256 + c] / fmaxf((float)(sh[1] - sh[0]), 1.0f);
  if (flags[0]) ((unsigned short*)out)[(size_t)g * 256 + c] = f2b(res);
  else          ((float*)out)[(size_t)g * 256 + c] = res;
}

extern "C" void kernel_launch(void* const* d_in, const int* in_sizes, int n_in,
                              void* d_out, int out_size, void* d_ws, size_t ws_size,
                              hipStream_t stream) {
  const void* x    = d_in[0];
  const int*  ei   = (const int*)d_in[1];
  const int*  batch= (const int*)d_in[2];

  char* ws = (char*)d_ws;
  int*            flags = (int*)(ws + OFF_FLAGS);
  unsigned short* Wb    = (unsigned short*)(ws + OFF_WB);
  unsigned short* Wp0   = (unsigned short*)(ws + OFF_WP0);
  unsigned short* Wp1   = (unsigned short*)(ws + OFF_WP1);
  unsigned short* Wp2   = (unsigned short*)(ws + OFF_WP2);
  unsigned short* Wp3   = (unsigned short*)(ws + OFF_WP3);
  int*            cnts  = (int*)(ws + OFF_CNT);
  int*            rowp  = (int*)(ws + OFF_ROWPTR);
  int*            curs  = (int*)(ws + OFF_CURSOR);
  unsigned short* ssrc  = (unsigned short*)(ws + OFF_SSRC);
  unsigned short* A     = (unsigned short*)(ws + OFF_A);
  unsigned short* B     = (unsigned short*)(ws + OFF_B);
  unsigned short* C     = (unsigned short*)(ws + OFF_C);
  float*          pool32= (float*)(ws + OFF_POOL32);
  int*            bsum  = (int*)(ws + OFF_BSUM);
  int*            boff  = (int*)(ws + OFF_BOFF);

  detect_kernel<<<1, 256, 0, stream>>>((const unsigned int*)x, (const unsigned int*)ei, flags);

  pack_w<<<16, 256, 0, stream>>>(d_in[3], Wp0, 128, flags);
  pack_w<<<32, 256, 0, stream>>>(d_in[5], Wp1, 256, flags);
  pack_w<<<32, 256, 0, stream>>>(d_in[7], Wp2, 256, flags);
  pack_w<<<32, 256, 0, stream>>>(d_in[9], Wp3, 256, flags);
  pack_bias<<<4, 256, 0, stream>>>(d_in[4], d_in[6], d_in[8], d_in[10], Wb, flags);

  zero_ws<<<196, 256, 0, stream>>>(cnts, pool32);
  hist_kernel<<<3125, 256, 0, stream>>>(ei, cnts, flags);
  scan_blocks<<<SCAN_BLOCKS, 256, 0, stream>>>(cnts, rowp, bsum);
  scan_sums<<<1, 256, 0, stream>>>(bsum, boff);
  scan_add<<<SCAN_BLOCKS, 256, 0, stream>>>(rowp, curs, boff);
  fill_kernel<<<3125, 256, 0, stream>>>(ei, curs, ssrc, flags);

  // layer 1
  conv_to_bf16<<<3125, 256, 0, stream>>>(x, A, 800000, flags);
  gather_kernel<<<6250, 256, 0, stream>>>(A, rowp, ssrc, B, 128);
  gemm_relu<<<3125, 256, 0, stream>>>(B, Wp0, Wb, 0, C, 128);   // t  -> C
  gemm_relu<<<3125, 256, 0, stream>>>(C, Wp1, Wb, 1, B, 256);   // h1 -> B

  // layer 2
  gather_kernel<<<12500, 256, 0, stream>>>(B, rowp, ssrc, C, 256);
  gemm_relu<<<3125, 256, 0, stream>>>(C, Wp2, Wb, 2, B, 256);   // t2 -> B
  gemm_relu<<<3125, 256, 0, stream>>>(B, Wp3, Wb, 3, C, 256);   // h2 -> C

  // pool
  pool_partial<<<(N_NODES + POOL_ROWS - 1) / POOL_ROWS, 256, 0, stream>>>(C, batch, pool32, flags);
  pool_final<<<N_GRAPHS, 256, 0, stream>>>(pool32, batch, d_out, flags);
}

// Round 6
// 441.254 us; speedup vs baseline: 10.2025x; 1.0963x over previous
//
#include <hip/hip_runtime.h>

// ---------------------------------------------------------------------------
// GIN (2 layers) + global mean pool, MI355X (gfx950).
// R6: fuse gather into GEMM A-operand (LDS tile), merge prep kernels,
// per-element weight packing. 12 dispatches (was 19).
//
// ws: [flags][Wb][Wp0..3][counts][rowptr][cursor][ssrc u16][A][B][C][pool32][bsum][boff]
// Pipeline:
//   detect+zero | prep(conv+hist+packs+bias) | scan x3 | fill
//   fused(A,D=128,Wp0) -> t(C) | gemm(C,Wp1) -> h1(B)
//   fused(B,D=256,Wp2) -> t2(C) | gemm(C,Wp3) -> h2(B)
//   pool_partial(B) | pool_final
// ---------------------------------------------------------------------------

typedef __bf16 bf16x8 __attribute__((ext_vector_type(8)));
typedef float f32x4 __attribute__((ext_vector_type(4)));

#define N_NODES 50000
#define N_EDGES 800000
#define N_GRAPHS 64
#define POOL_ROWS 128
#define SCAN_BLOCKS 196

// prep kernel block ranges
#define PB_CONV0 0
#define PB_HIST0 3125
#define PB_P0    6250   // pack W1_0 (K=128): 32768 elems -> 128 blocks
#define PB_P1    6378   // pack W2_0 (K=256): 65536 -> 256
#define PB_P2    6634
#define PB_P3    6890
#define PB_BIAS  7146   // 4 blocks
#define PB_TOTAL 7150

#define OFF_FLAGS  0ull
#define OFF_WB     64ull
#define OFF_WP0    4096ull
#define OFF_WP1    (OFF_WP0 + 65536ull)
#define OFF_WP2    (OFF_WP1 + 131072ull)
#define OFF_WP3    (OFF_WP2 + 131072ull)
#define OFF_CNT    462848ull
#define OFF_ROWPTR 662864ull
#define OFF_CURSOR 862880ull
#define OFF_SSRC   1062912ull
#define OFF_A      2662912ull               // 12.8 MB
#define OFF_B      15462912ull              // 25.6 MB
#define OFF_C      41062912ull              // 25.6 MB
#define OFF_POOL32 66662912ull              // 64 KB
#define OFF_BSUM   66728448ull
#define OFF_BOFF   66729472ull

__device__ __forceinline__ float b2f(unsigned short u) {
  union { unsigned int i; float f; } v; v.i = ((unsigned int)u) << 16; return v.f;
}
__device__ __forceinline__ float b2f_lo(unsigned int u) {
  union { unsigned int i; float f; } v; v.i = u << 16; return v.f;
}
__device__ __forceinline__ float b2f_hi(unsigned int u) {
  union { unsigned int i; float f; } v; v.i = u & 0xffff0000u; return v.f;
}
__device__ __forceinline__ unsigned short f2b(float f) {
  union { unsigned int i; float f; } v; v.f = f;
  unsigned int r = v.i + 0x7fffu + ((v.i >> 16) & 1u);
  return (unsigned short)(r >> 16);
}

// ---- block 0: dtype detect; blocks 1..196: zero counts + pool accumulator
__global__ void detect_zero(const unsigned int* __restrict__ xw,
                            const unsigned int* __restrict__ eiw,
                            int* __restrict__ flags,
                            int* __restrict__ counts, float* __restrict__ pool32) {
  if (blockIdx.x == 0) {
    __shared__ int s_f[256], s_i[256];
    int t = threadIdx.x;
    int fh = 0, iz = 0;
    for (int i = t; i < 1024; i += 256) {
      unsigned int e = (xw[i] >> 7) & 0xFFu;
      fh += (e >= 115u && e <= 130u) ? 1 : 0;
      iz += (eiw[2 * i + 1] == 0u) ? 1 : 0;
    }
    s_f[t] = fh; s_i[t] = iz;
    __syncthreads();
    for (int s = 128; s > 0; s >>= 1) {
      if (t < s) { s_f[t] += s_f[t + s]; s_i[t] += s_i[t + s]; }
      __syncthreads();
    }
    if (t == 0) { flags[0] = s_f[0] > 512 ? 1 : 0; flags[1] = s_i[0] > 512 ? 1 : 0; }
  } else {
    int i = (blockIdx.x - 1) * 256 + threadIdx.x;
    if (i < N_NODES) counts[i] = 0;
    if (i < N_GRAPHS * 256) pool32[i] = 0.f;
  }
}

// ---- prep: conv_to_bf16 + hist + 4 weight packs + bias (flags-dependent only)
__device__ __forceinline__ void pack_w_elem(const void* W, unsigned short* Wp,
                                            int e, int isb) {
  // linear read index == e; out = (((kb*256+n)*4+q)*8+j)
  int n = e & 255;
  int krow = e >> 8;
  int kb = krow >> 5, r = krow & 31;
  int q = r >> 3, j = r & 7;
  size_t out = ((((size_t)(kb << 8) + n) << 2) + q) * 8 + j;
  Wp[out] = isb ? ((const unsigned short*)W)[e] : f2b(((const float*)W)[e]);
}

__global__ void prep_kernel(const void* __restrict__ x, const int* __restrict__ ei,
                            const void* W0, const void* W1, const void* W2, const void* W3,
                            const void* b0, const void* b1, const void* b2, const void* b3,
                            unsigned short* __restrict__ A,
                            int* __restrict__ counts,
                            unsigned short* __restrict__ Wp0, unsigned short* __restrict__ Wp1,
                            unsigned short* __restrict__ Wp2, unsigned short* __restrict__ Wp3,
                            unsigned short* __restrict__ Wb,
                            const int* __restrict__ flags) {
  int b = blockIdx.x, t = threadIdx.x;
  int isb = flags[0];
  if (b < PB_HIST0) {                       // conv: 8 elems/thread, exact 800000
    int i = b * 256 + t;
    if (isb) {
      ((uint4*)A)[i] = ((const uint4*)x)[i];
    } else {
      const float4* f = (const float4*)x;
      float4 a = f[2 * i], c = f[2 * i + 1];
      ushort4 o0; o0.x = f2b(a.x); o0.y = f2b(a.y); o0.z = f2b(a.z); o0.w = f2b(a.w);
      ushort4 o1; o1.x = f2b(c.x); o1.y = f2b(c.y); o1.z = f2b(c.z); o1.w = f2b(c.w);
      ((ushort4*)A)[2 * i] = o0;
      ((ushort4*)A)[2 * i + 1] = o1;
    }
  } else if (b < PB_P0) {                   // hist, exact 800000
    int e = (b - PB_HIST0) * 256 + t;
    int dst = flags[1] ? ei[2 * (N_EDGES + e)] : ei[N_EDGES + e];
    atomicAdd(&counts[dst], 1);
  } else if (b < PB_P1) {
    pack_w_elem(W0, Wp0, (b - PB_P0) * 256 + t, isb);
  } else if (b < PB_P2) {
    pack_w_elem(W1, Wp1, (b - PB_P1) * 256 + t, isb);
  } else if (b < PB_P3) {
    pack_w_elem(W2, Wp2, (b - PB_P2) * 256 + t, isb);
  } else if (b < PB_BIAS) {
    pack_w_elem(W3, Wp3, (b - PB_P3) * 256 + t, isb);
  } else {
    int i = (b - PB_BIAS) * 256 + t;        // 0..1023
    const void* p = (i < 256) ? b0 : (i < 512) ? b1 : (i < 768) ? b2 : b3;
    int n = i & 255;
    Wb[i] = isb ? ((const unsigned short*)p)[n] : f2b(((const float*)p)[n]);
  }
}

// ---- 3-stage scan
__global__ void scan_blocks(const int* __restrict__ counts,
                            int* __restrict__ rowptr, int* __restrict__ bsum) {
  __shared__ int sd[256];
  int t = threadIdx.x;
  int i = blockIdx.x * 256 + t;
  int v = (i < N_NODES) ? counts[i] : 0;
  sd[t] = v;
  __syncthreads();
  for (int off = 1; off < 256; off <<= 1) {
    int u = (t >= off) ? sd[t - off] : 0;
    __syncthreads();
    sd[t] += u;
    __syncthreads();
  }
  if (i < N_NODES) rowptr[i] = sd[t] - v;
  if (t == 255) bsum[blockIdx.x] = sd[255];
}

__global__ void scan_sums(const int* __restrict__ bsum, int* __restrict__ boff) {
  __shared__ int sd[256];
  int t = threadIdx.x;
  int v = (t < SCAN_BLOCKS) ? bsum[t] : 0;
  sd[t] = v;
  __syncthreads();
  for (int off = 1; off < 256; off <<= 1) {
    int u = (t >= off) ? sd[t - off] : 0;
    __syncthreads();
    sd[t] += u;
    __syncthreads();
  }
  if (t < SCAN_BLOCKS) boff[t] = sd[t] - v;
}

__global__ void scan_add(int* __restrict__ rowptr, int* __restrict__ cursor,
                         const int* __restrict__ boff) {
  int i = blockIdx.x * 256 + threadIdx.x;
  if (i < N_NODES) {
    int v = rowptr[i] + boff[blockIdx.x];
    rowptr[i] = v;
    cursor[i] = v;
  }
  if (i == 0) rowptr[N_NODES] = N_EDGES;
}

__global__ void fill_kernel(const int* __restrict__ ei, int* __restrict__ cursor,
                            unsigned short* __restrict__ ssrc,
                            const int* __restrict__ flags) {
  int e = blockIdx.x * blockDim.x + threadIdx.x;
  if (e >= N_EDGES) return;
  int is64 = flags[1];
  int src = is64 ? ei[2 * e] : ei[e];
  int dst = is64 ? ei[2 * (N_EDGES + e)] : ei[N_EDGES + e];
  int pos = atomicAdd(&cursor[dst], 1);
  ssrc[pos] = (unsigned short)src;
}

// ---- fused gather + GEMM: C = relu((feat + Agg(feat)) @ W + b), D == K.
// Block = 4 waves, tile 16 nodes x 256 cols. Gather phase: 16-lane group per
// node (4 nodes/wave), 16B loads, f32 accum, bf16 round into LDS A-tile
// (row stride D+8 elems -> 2-way-free LDS banking). MFMA phase: as gemm_relu
// but A-frags from LDS.
__global__ void fused_gather_gemm(const unsigned short* __restrict__ feat,
                                  const int* __restrict__ rowptr,
                                  const unsigned short* __restrict__ ssrc,
                                  const unsigned short* __restrict__ Wp,
                                  const unsigned short* __restrict__ Wb, int bias_row,
                                  unsigned short* __restrict__ C, int D) {
  __shared__ __align__(16) unsigned short Alds[16 * 264];
  const int S = D + 8;
  const int row0 = blockIdx.x << 4;
  const int lane = threadIdx.x & 63;
  const int wave = threadIdx.x >> 6;

  {  // gather phase
    int sub = lane >> 4;                 // node slot within wave
    int l = lane & 15;                   // lane within group
    int nl = (wave << 2) + sub;          // local row 0..15
    int node = row0 + nl;
    int beg = rowptr[node], end = rowptr[node + 1];
    int npass = D >> 7;                  // 1 (D=128) or 2 (D=256)
    for (int h = 0; h < npass; ++h) {
      int c = (l << 3) + (h << 7);
      uint4 sv = *(const uint4*)(feat + (size_t)node * D + c);
      float a0 = b2f_lo(sv.x), a1 = b2f_hi(sv.x);
      float a2 = b2f_lo(sv.y), a3 = b2f_hi(sv.y);
      float a4 = b2f_lo(sv.z), a5 = b2f_hi(sv.z);
      float a6 = b2f_lo(sv.w), a7 = b2f_hi(sv.w);
      for (int i = beg; i < end; ++i) {
        int src = ssrc[i];
        uint4 v = *(const uint4*)(feat + (size_t)src * D + c);
        a0 += b2f_lo(v.x); a1 += b2f_hi(v.x);
        a2 += b2f_lo(v.y); a3 += b2f_hi(v.y);
        a4 += b2f_lo(v.z); a5 += b2f_hi(v.z);
        a6 += b2f_lo(v.w); a7 += b2f_hi(v.w);
      }
      uint4 o;
      o.x = ((unsigned int)f2b(a1) << 16) | f2b(a0);
      o.y = ((unsigned int)f2b(a3) << 16) | f2b(a2);
      o.z = ((unsigned int)f2b(a5) << 16) | f2b(a4);
      o.w = ((unsigned int)f2b(a7) << 16) | f2b(a6);
      *(uint4*)(&Alds[nl * S + c]) = o;
    }
  }
  __syncthreads();

  // MFMA phase
  const int m = lane & 15;
  const int q = lane >> 4;
  f32x4 acc[4];
#pragma unroll
  for (int t = 0; t < 4; ++t) acc[t] = (f32x4){0.f, 0.f, 0.f, 0.f};

  const unsigned short* arow = &Alds[m * S + (q << 3)];
  const int nb = (wave << 6) + m;
  const int kblocks = D >> 5;
  for (int kb = 0; kb < kblocks; ++kb) {
    bf16x8 af = *(const bf16x8*)(arow + (kb << 5));
    const unsigned short* wp = Wp + (((size_t)(kb << 8) + nb) * 4 + q) * 8;
    bf16x8 b0 = *(const bf16x8*)(wp);
    bf16x8 b1 = *(const bf16x8*)(wp + 512);
    bf16x8 b2 = *(const bf16x8*)(wp + 1024);
    bf16x8 b3 = *(const bf16x8*)(wp + 1536);
    acc[0] = __builtin_amdgcn_mfma_f32_16x16x32_bf16(af, b0, acc[0], 0, 0, 0);
    acc[1] = __builtin_amdgcn_mfma_f32_16x16x32_bf16(af, b1, acc[1], 0, 0, 0);
    acc[2] = __builtin_amdgcn_mfma_f32_16x16x32_bf16(af, b2, acc[2], 0, 0, 0);
    acc[3] = __builtin_amdgcn_mfma_f32_16x16x32_bf16(af, b3, acc[3], 0, 0, 0);
  }
#pragma unroll
  for (int t = 0; t < 4; ++t) {
    int n = (wave << 6) + (t << 4) + m;
    float bv = b2f(Wb[bias_row * 256 + n]);
#pragma unroll
    for (int i = 0; i < 4; ++i) {
      int r = row0 + (q << 2) + i;
      float v = fmaxf(acc[t][i] + bv, 0.f);
      C[(size_t)r * 256 + n] = f2b(v);
    }
  }
}

// ---- plain GEMM: C(M x 256) = relu(A(M x K) @ W + b), bf16.
__global__ void gemm_relu(const unsigned short* __restrict__ A,
                          const unsigned short* __restrict__ Wp,
                          const unsigned short* __restrict__ Wb, int bias_row,
                          unsigned short* __restrict__ C, int K) {
  const int row0 = blockIdx.x << 4;
  const int lane = threadIdx.x & 63;
  const int wave = threadIdx.x >> 6;
  const int m = lane & 15;
  const int q = lane >> 4;
  f32x4 acc[4];
#pragma unroll
  for (int t = 0; t < 4; ++t) acc[t] = (f32x4){0.f, 0.f, 0.f, 0.f};

  const unsigned short* arow = A + (size_t)(row0 + m) * K + (q << 3);
  const int nb = (wave << 6) + m;
  const int kblocks = K >> 5;
  for (int kb = 0; kb < kblocks; ++kb) {
    bf16x8 af = *(const bf16x8*)(arow + (kb << 5));
    const unsigned short* wp = Wp + (((size_t)(kb << 8) + nb) * 4 + q) * 8;
    bf16x8 b0 = *(const bf16x8*)(wp);
    bf16x8 b1 = *(const bf16x8*)(wp + 512);
    bf16x8 b2 = *(const bf16x8*)(wp + 1024);
    bf16x8 b3 = *(const bf16x8*)(wp + 1536);
    acc[0] = __builtin_amdgcn_mfma_f32_16x16x32_bf16(af, b0, acc[0], 0, 0, 0);
    acc[1] = __builtin_amdgcn_mfma_f32_16x16x32_bf16(af, b1, acc[1], 0, 0, 0);
    acc[2] = __builtin_amdgcn_mfma_f32_16x16x32_bf16(af, b2, acc[2], 0, 0, 0);
    acc[3] = __builtin_amdgcn_mfma_f32_16x16x32_bf16(af, b3, acc[3], 0, 0, 0);
  }
#pragma unroll
  for (int t = 0; t < 4; ++t) {
    int n = (wave << 6) + (t << 4) + m;
    float bv = b2f(Wb[bias_row * 256 + n]);
#pragma unroll
    for (int i = 0; i < 4; ++i) {
      int r = row0 + (q << 2) + i;
      float v = fmaxf(acc[t][i] + bv, 0.f);
      C[(size_t)r * 256 + n] = f2b(v);
    }
  }
}

// ---- parallel mean pool
__global__ void pool_partial(const unsigned short* __restrict__ h2,
                             const int* __restrict__ batch,
                             float* __restrict__ pool32,
                             const int* __restrict__ flags) {
  __shared__ int sg[POOL_ROWS];
  int r0 = blockIdx.x * POOL_ROWS;
  int nr = N_NODES - r0; if (nr > POOL_ROWS) nr = POOL_ROWS;
  int is64 = flags[1];
  for (int i = threadIdx.x; i < nr; i += 256)
    sg[i] = is64 ? batch[2 * (r0 + i)] : batch[r0 + i];
  __syncthreads();
  int c = threadIdx.x;
  float acc = 0.f;
  int cur = sg[0];
  for (int i = 0; i < nr; ++i) {
    int g = sg[i];
    if (g != cur) {
      unsafeAtomicAdd(&pool32[cur * 256 + c], acc);
      acc = 0.f; cur = g;
    }
    acc += b2f(h2[(size_t)(r0 + i) * 256 + c]);
  }
  unsafeAtomicAdd(&pool32[cur * 256 + c], acc);
}

__device__ __forceinline__ int lower_bound(const int* a, int n, int v, int is64) {
  int lo = 0, hi = n;
  while (lo < hi) {
    int mid = (lo + hi) >> 1;
    int bv = is64 ? a[2 * mid] : a[mid];
    if (bv < v) lo = mid + 1; else hi = mid;
  }
  return lo;
}

__global__ void pool_final(const float* __restrict__ pool32,
                           const int* __restrict__ batch,
                           void* __restrict__ out,
                           const int* __restrict__ flags) {
  __shared__ int sh[2];
  int g = blockIdx.x;
  int is64 = flags[1];
  if (threadIdx.x == 0) sh[0] = lower_bound(batch, N_NODES, g, is64);
  if (threadIdx.x == 1) sh[1] = lower_bound(batch, N_NODES, g + 1, is64);
  __syncthreads();
  int c = threadIdx.x;
  float res = pool32[g * 256 + c] / fmaxf((float)(sh[1] - sh[0]), 1.0f);
  if (flags[0]) ((unsigned short*)out)[(size_t)g * 256 + c] = f2b(res);
  else          ((float*)out)[(size_t)g * 256 + c] = res;
}

extern "C" void kernel_launch(void* const* d_in, const int* in_sizes, int n_in,
                              void* d_out, int out_size, void* d_ws, size_t ws_size,
                              hipStream_t stream) {
  const void* x    = d_in[0];
  const int*  ei   = (const int*)d_in[1];
  const int*  batch= (const int*)d_in[2];

  char* ws = (char*)d_ws;
  int*            flags = (int*)(ws + OFF_FLAGS);
  unsigned short* Wb    = (unsigned short*)(ws + OFF_WB);
  unsigned short* Wp0   = (unsigned short*)(ws + OFF_WP0);
  unsigned short* Wp1   = (unsigned short*)(ws + OFF_WP1);
  unsigned short* Wp2   = (unsigned short*)(ws + OFF_WP2);
  unsigned short* Wp3   = (unsigned short*)(ws + OFF_WP3);
  int*            cnts  = (int*)(ws + OFF_CNT);
  int*            rowp  = (int*)(ws + OFF_ROWPTR);
  int*            curs  = (int*)(ws + OFF_CURSOR);
  unsigned short* ssrc  = (unsigned short*)(ws + OFF_SSRC);
  unsigned short* A     = (unsigned short*)(ws + OFF_A);
  unsigned short* B     = (unsigned short*)(ws + OFF_B);
  unsigned short* C     = (unsigned short*)(ws + OFF_C);
  float*          pool32= (float*)(ws + OFF_POOL32);
  int*            bsum  = (int*)(ws + OFF_BSUM);
  int*            boff  = (int*)(ws + OFF_BOFF);

  detect_zero<<<197, 256, 0, stream>>>((const unsigned int*)x, (const unsigned int*)ei,
                                       flags, cnts, pool32);
  prep_kernel<<<PB_TOTAL, 256, 0, stream>>>(x, ei,
                                            d_in[3], d_in[5], d_in[7], d_in[9],
                                            d_in[4], d_in[6], d_in[8], d_in[10],
                                            A, cnts, Wp0, Wp1, Wp2, Wp3, Wb, flags);
  scan_blocks<<<SCAN_BLOCKS, 256, 0, stream>>>(cnts, rowp, bsum);
  scan_sums<<<1, 256, 0, stream>>>(bsum, boff);
  scan_add<<<SCAN_BLOCKS, 256, 0, stream>>>(rowp, curs, boff);
  fill_kernel<<<3125, 256, 0, stream>>>(ei, curs, ssrc, flags);

  // layer 1
  fused_gather_gemm<<<3125, 256, 0, stream>>>(A, rowp, ssrc, Wp0, Wb, 0, C, 128); // t -> C
  gemm_relu<<<3125, 256, 0, stream>>>(C, Wp1, Wb, 1, B, 256);                     // h1 -> B

  // layer 2
  fused_gather_gemm<<<3125, 256, 0, stream>>>(B, rowp, ssrc, Wp2, Wb, 2, C, 256); // t2 -> C
  gemm_relu<<<3125, 256, 0, stream>>>(C, Wp3, Wb, 3, B, 256);                     // h2 -> B

  // pool
  pool_partial<<<(N_NODES + POOL_ROWS - 1) / POOL_ROWS, 256, 0, stream>>>(B, batch, pool32, flags);
  pool_final<<<N_GRAPHS, 256, 0, stream>>>(pool32, batch, d_out, flags);
}

// Round 7
// 386.241 us; speedup vs baseline: 11.6557x; 1.1424x over previous
//
#include <hip/hip_runtime.h>

// ---------------------------------------------------------------------------
// GIN (2 layers) + global mean pool, MI355X (gfx950).
// R7: single-pass gather w/ 2-edge unroll in fused kernels (was 2 serial
// passes at half MLP); fuse mean-pool into last GEMM epilogue (no h2
// materialization); bf16 inputs skip the canonicalization copy.
//
// Pipeline (11 dispatches):
//   detect+zero | prep(conv+hist+packs+bias) | scan x3 | fill
//   fused(x/A,D=128,Wp0) -> t(C) | gemm(C,Wp1) -> h1(B)
//   fused(B,D=256,Wp2) -> t2(C) | gemm_pool(C,Wp3) -> pool32 | pool_final
// ---------------------------------------------------------------------------

typedef __bf16 bf16x8 __attribute__((ext_vector_type(8)));
typedef float f32x4 __attribute__((ext_vector_type(4)));

#define N_NODES 50000
#define N_EDGES 800000
#define N_GRAPHS 64
#define SCAN_BLOCKS 196

// prep kernel block ranges
#define PB_HIST0 3125
#define PB_P0    6250
#define PB_P1    6378
#define PB_P2    6634
#define PB_P3    6890
#define PB_BIAS  7146
#define PB_TOTAL 7150

#define OFF_FLAGS  0ull
#define OFF_WB     64ull
#define OFF_WP0    4096ull
#define OFF_WP1    (OFF_WP0 + 65536ull)
#define OFF_WP2    (OFF_WP1 + 131072ull)
#define OFF_WP3    (OFF_WP2 + 131072ull)
#define OFF_CNT    462848ull
#define OFF_ROWPTR 662864ull
#define OFF_CURSOR 862880ull
#define OFF_SSRC   1062912ull
#define OFF_A      2662912ull               // 12.8 MB
#define OFF_B      15462912ull              // 25.6 MB
#define OFF_C      41062912ull              // 25.6 MB
#define OFF_POOL32 66662912ull              // 64 KB
#define OFF_BSUM   66728448ull
#define OFF_BOFF   66729472ull

__device__ __forceinline__ float b2f(unsigned short u) {
  union { unsigned int i; float f; } v; v.i = ((unsigned int)u) << 16; return v.f;
}
__device__ __forceinline__ float b2f_lo(unsigned int u) {
  union { unsigned int i; float f; } v; v.i = u << 16; return v.f;
}
__device__ __forceinline__ float b2f_hi(unsigned int u) {
  union { unsigned int i; float f; } v; v.i = u & 0xffff0000u; return v.f;
}
__device__ __forceinline__ unsigned short f2b(float f) {
  union { unsigned int i; float f; } v; v.f = f;
  unsigned int r = v.i + 0x7fffu + ((v.i >> 16) & 1u);
  return (unsigned short)(r >> 16);
}

// ---- block 0: dtype detect; blocks 1..196: zero counts + pool accumulator
__global__ void detect_zero(const unsigned int* __restrict__ xw,
                            const unsigned int* __restrict__ eiw,
                            int* __restrict__ flags,
                            int* __restrict__ counts, float* __restrict__ pool32) {
  if (blockIdx.x == 0) {
    __shared__ int s_f[256], s_i[256];
    int t = threadIdx.x;
    int fh = 0, iz = 0;
    for (int i = t; i < 1024; i += 256) {
      unsigned int e = (xw[i] >> 7) & 0xFFu;
      fh += (e >= 115u && e <= 130u) ? 1 : 0;
      iz += (eiw[2 * i + 1] == 0u) ? 1 : 0;
    }
    s_f[t] = fh; s_i[t] = iz;
    __syncthreads();
    for (int s = 128; s > 0; s >>= 1) {
      if (t < s) { s_f[t] += s_f[t + s]; s_i[t] += s_i[t + s]; }
      __syncthreads();
    }
    if (t == 0) { flags[0] = s_f[0] > 512 ? 1 : 0; flags[1] = s_i[0] > 512 ? 1 : 0; }
  } else {
    int i = (blockIdx.x - 1) * 256 + threadIdx.x;
    if (i < N_NODES) counts[i] = 0;
    if (i < N_GRAPHS * 256) pool32[i] = 0.f;
  }
}

// ---- prep: conv(f32 only) + hist + 4 weight packs + bias
__device__ __forceinline__ void pack_w_elem(const void* W, unsigned short* Wp,
                                            int e, int isb) {
  int n = e & 255;
  int krow = e >> 8;
  int kb = krow >> 5, r = krow & 31;
  int q = r >> 3, j = r & 7;
  size_t out = ((((size_t)(kb << 8) + n) << 2) + q) * 8 + j;
  Wp[out] = isb ? ((const unsigned short*)W)[e] : f2b(((const float*)W)[e]);
}

__global__ void prep_kernel(const void* __restrict__ x, const int* __restrict__ ei,
                            const void* W0, const void* W1, const void* W2, const void* W3,
                            const void* b0, const void* b1, const void* b2, const void* b3,
                            unsigned short* __restrict__ A,
                            int* __restrict__ counts,
                            unsigned short* __restrict__ Wp0, unsigned short* __restrict__ Wp1,
                            unsigned short* __restrict__ Wp2, unsigned short* __restrict__ Wp3,
                            unsigned short* __restrict__ Wb,
                            const int* __restrict__ flags) {
  int b = blockIdx.x, t = threadIdx.x;
  int isb = flags[0];
  if (b < PB_HIST0) {                       // conv 8 elems/thread (f32 path only)
    if (!isb) {
      int i = b * 256 + t;
      const float4* f = (const float4*)x;
      float4 a = f[2 * i], c = f[2 * i + 1];
      ushort4 o0; o0.x = f2b(a.x); o0.y = f2b(a.y); o0.z = f2b(a.z); o0.w = f2b(a.w);
      ushort4 o1; o1.x = f2b(c.x); o1.y = f2b(c.y); o1.z = f2b(c.z); o1.w = f2b(c.w);
      ((ushort4*)A)[2 * i] = o0;
      ((ushort4*)A)[2 * i + 1] = o1;
    }
  } else if (b < PB_P0) {                   // hist, exact 800000
    int e = (b - PB_HIST0) * 256 + t;
    int dst = flags[1] ? ei[2 * (N_EDGES + e)] : ei[N_EDGES + e];
    atomicAdd(&counts[dst], 1);
  } else if (b < PB_P1) {
    pack_w_elem(W0, Wp0, (b - PB_P0) * 256 + t, isb);
  } else if (b < PB_P2) {
    pack_w_elem(W1, Wp1, (b - PB_P1) * 256 + t, isb);
  } else if (b < PB_P3) {
    pack_w_elem(W2, Wp2, (b - PB_P2) * 256 + t, isb);
  } else if (b < PB_BIAS) {
    pack_w_elem(W3, Wp3, (b - PB_P3) * 256 + t, isb);
  } else {
    int i = (b - PB_BIAS) * 256 + t;
    const void* p = (i < 256) ? b0 : (i < 512) ? b1 : (i < 768) ? b2 : b3;
    int n = i & 255;
    Wb[i] = isb ? ((const unsigned short*)p)[n] : f2b(((const float*)p)[n]);
  }
}

// ---- 3-stage scan
__global__ void scan_blocks(const int* __restrict__ counts,
                            int* __restrict__ rowptr, int* __restrict__ bsum) {
  __shared__ int sd[256];
  int t = threadIdx.x;
  int i = blockIdx.x * 256 + t;
  int v = (i < N_NODES) ? counts[i] : 0;
  sd[t] = v;
  __syncthreads();
  for (int off = 1; off < 256; off <<= 1) {
    int u = (t >= off) ? sd[t - off] : 0;
    __syncthreads();
    sd[t] += u;
    __syncthreads();
  }
  if (i < N_NODES) rowptr[i] = sd[t] - v;
  if (t == 255) bsum[blockIdx.x] = sd[255];
}

__global__ void scan_sums(const int* __restrict__ bsum, int* __restrict__ boff) {
  __shared__ int sd[256];
  int t = threadIdx.x;
  int v = (t < SCAN_BLOCKS) ? bsum[t] : 0;
  sd[t] = v;
  __syncthreads();
  for (int off = 1; off < 256; off <<= 1) {
    int u = (t >= off) ? sd[t - off] : 0;
    __syncthreads();
    sd[t] += u;
    __syncthreads();
  }
  if (t < SCAN_BLOCKS) boff[t] = sd[t] - v;
}

__global__ void scan_add(int* __restrict__ rowptr, int* __restrict__ cursor,
                         const int* __restrict__ boff) {
  int i = blockIdx.x * 256 + threadIdx.x;
  if (i < N_NODES) {
    int v = rowptr[i] + boff[blockIdx.x];
    rowptr[i] = v;
    cursor[i] = v;
  }
  if (i == 0) rowptr[N_NODES] = N_EDGES;
}

__global__ void fill_kernel(const int* __restrict__ ei, int* __restrict__ cursor,
                            unsigned short* __restrict__ ssrc,
                            const int* __restrict__ flags) {
  int e = blockIdx.x * blockDim.x + threadIdx.x;
  if (e >= N_EDGES) return;
  int is64 = flags[1];
  int src = is64 ? ei[2 * e] : ei[e];
  int dst = is64 ? ei[2 * (N_EDGES + e)] : ei[N_EDGES + e];
  int pos = atomicAdd(&cursor[dst], 1);
  ssrc[pos] = (unsigned short)src;
}

// ---- fused gather + GEMM: C = relu((feat + Agg(feat)) @ W + b), D == K.
// Gather: 16-lane group per node, single pass over edges (2x uint4 for D=256),
// 2-edge unroll. featCanon/featRaw selected by flags[0] (bf16 inputs skip copy).
__global__ void fused_gather_gemm(const unsigned short* __restrict__ featCanon,
                                  const unsigned short* __restrict__ featRaw,
                                  const int* __restrict__ rowptr,
                                  const unsigned short* __restrict__ ssrc,
                                  const unsigned short* __restrict__ Wp,
                                  const unsigned short* __restrict__ Wb, int bias_row,
                                  unsigned short* __restrict__ C, int D,
                                  const int* __restrict__ flags) {
  __shared__ __align__(16) unsigned short Alds[16 * 264];
  const int S = D + 8;
  const int row0 = blockIdx.x << 4;
  const int lane = threadIdx.x & 63;
  const int wave = threadIdx.x >> 6;
  const unsigned short* feat = flags[0] ? featRaw : featCanon;

  {  // gather phase
    int sub = lane >> 4;
    int l = lane & 15;
    int nl = (wave << 2) + sub;
    int node = row0 + nl;
    int beg = rowptr[node], end = rowptr[node + 1];
    int c = l << 3;
    if (D == 256) {
      const unsigned short* sp = feat + (size_t)node * 256 + c;
      uint4 sv0 = *(const uint4*)sp;
      uint4 sv1 = *(const uint4*)(sp + 128);
      float a0 = b2f_lo(sv0.x), a1 = b2f_hi(sv0.x), a2 = b2f_lo(sv0.y), a3 = b2f_hi(sv0.y);
      float a4 = b2f_lo(sv0.z), a5 = b2f_hi(sv0.z), a6 = b2f_lo(sv0.w), a7 = b2f_hi(sv0.w);
      float a8 = b2f_lo(sv1.x), a9 = b2f_hi(sv1.x), aA = b2f_lo(sv1.y), aB = b2f_hi(sv1.y);
      float aC = b2f_lo(sv1.z), aD = b2f_hi(sv1.z), aE = b2f_lo(sv1.w), aF = b2f_hi(sv1.w);
      int i = beg;
      for (; i + 1 < end; i += 2) {
        int s0 = ssrc[i], s1 = ssrc[i + 1];
        const unsigned short* p0 = feat + (size_t)s0 * 256 + c;
        const unsigned short* p1 = feat + (size_t)s1 * 256 + c;
        uint4 v00 = *(const uint4*)p0;
        uint4 v01 = *(const uint4*)(p0 + 128);
        uint4 v10 = *(const uint4*)p1;
        uint4 v11 = *(const uint4*)(p1 + 128);
        a0 += b2f_lo(v00.x); a1 += b2f_hi(v00.x); a2 += b2f_lo(v00.y); a3 += b2f_hi(v00.y);
        a4 += b2f_lo(v00.z); a5 += b2f_hi(v00.z); a6 += b2f_lo(v00.w); a7 += b2f_hi(v00.w);
        a8 += b2f_lo(v01.x); a9 += b2f_hi(v01.x); aA += b2f_lo(v01.y); aB += b2f_hi(v01.y);
        aC += b2f_lo(v01.z); aD += b2f_hi(v01.z); aE += b2f_lo(v01.w); aF += b2f_hi(v01.w);
        a0 += b2f_lo(v10.x); a1 += b2f_hi(v10.x); a2 += b2f_lo(v10.y); a3 += b2f_hi(v10.y);
        a4 += b2f_lo(v10.z); a5 += b2f_hi(v10.z); a6 += b2f_lo(v10.w); a7 += b2f_hi(v10.w);
        a8 += b2f_lo(v11.x); a9 += b2f_hi(v11.x); aA += b2f_lo(v11.y); aB += b2f_hi(v11.y);
        aC += b2f_lo(v11.z); aD += b2f_hi(v11.z); aE += b2f_lo(v11.w); aF += b2f_hi(v11.w);
      }
      if (i < end) {
        const unsigned short* p0 = feat + (size_t)ssrc[i] * 256 + c;
        uint4 v00 = *(const uint4*)p0;
        uint4 v01 = *(const uint4*)(p0 + 128);
        a0 += b2f_lo(v00.x); a1 += b2f_hi(v00.x); a2 += b2f_lo(v00.y); a3 += b2f_hi(v00.y);
        a4 += b2f_lo(v00.z); a5 += b2f_hi(v00.z); a6 += b2f_lo(v00.w); a7 += b2f_hi(v00.w);
        a8 += b2f_lo(v01.x); a9 += b2f_hi(v01.x); aA += b2f_lo(v01.y); aB += b2f_hi(v01.y);
        aC += b2f_lo(v01.z); aD += b2f_hi(v01.z); aE += b2f_lo(v01.w); aF += b2f_hi(v01.w);
      }
      uint4 o0, o1;
      o0.x = ((unsigned int)f2b(a1) << 16) | f2b(a0);
      o0.y = ((unsigned int)f2b(a3) << 16) | f2b(a2);
      o0.z = ((unsigned int)f2b(a5) << 16) | f2b(a4);
      o0.w = ((unsigned int)f2b(a7) << 16) | f2b(a6);
      o1.x = ((unsigned int)f2b(a9) << 16) | f2b(a8);
      o1.y = ((unsigned int)f2b(aB) << 16) | f2b(aA);
      o1.z = ((unsigned int)f2b(aD) << 16) | f2b(aC);
      o1.w = ((unsigned int)f2b(aF) << 16) | f2b(aE);
      *(uint4*)(&Alds[nl * S + c]) = o0;
      *(uint4*)(&Alds[nl * S + c + 128]) = o1;
    } else {  // D == 128
      const unsigned short* sp = feat + (size_t)node * 128 + c;
      uint4 sv0 = *(const uint4*)sp;
      float a0 = b2f_lo(sv0.x), a1 = b2f_hi(sv0.x), a2 = b2f_lo(sv0.y), a3 = b2f_hi(sv0.y);
      float a4 = b2f_lo(sv0.z), a5 = b2f_hi(sv0.z), a6 = b2f_lo(sv0.w), a7 = b2f_hi(sv0.w);
      int i = beg;
      for (; i + 1 < end; i += 2) {
        int s0 = ssrc[i], s1 = ssrc[i + 1];
        uint4 v0 = *(const uint4*)(feat + (size_t)s0 * 128 + c);
        uint4 v1 = *(const uint4*)(feat + (size_t)s1 * 128 + c);
        a0 += b2f_lo(v0.x); a1 += b2f_hi(v0.x); a2 += b2f_lo(v0.y); a3 += b2f_hi(v0.y);
        a4 += b2f_lo(v0.z); a5 += b2f_hi(v0.z); a6 += b2f_lo(v0.w); a7 += b2f_hi(v0.w);
        a0 += b2f_lo(v1.x); a1 += b2f_hi(v1.x); a2 += b2f_lo(v1.y); a3 += b2f_hi(v1.y);
        a4 += b2f_lo(v1.z); a5 += b2f_hi(v1.z); a6 += b2f_lo(v1.w); a7 += b2f_hi(v1.w);
      }
      if (i < end) {
        uint4 v0 = *(const uint4*)(feat + (size_t)ssrc[i] * 128 + c);
        a0 += b2f_lo(v0.x); a1 += b2f_hi(v0.x); a2 += b2f_lo(v0.y); a3 += b2f_hi(v0.y);
        a4 += b2f_lo(v0.z); a5 += b2f_hi(v0.z); a6 += b2f_lo(v0.w); a7 += b2f_hi(v0.w);
      }
      uint4 o0;
      o0.x = ((unsigned int)f2b(a1) << 16) | f2b(a0);
      o0.y = ((unsigned int)f2b(a3) << 16) | f2b(a2);
      o0.z = ((unsigned int)f2b(a5) << 16) | f2b(a4);
      o0.w = ((unsigned int)f2b(a7) << 16) | f2b(a6);
      *(uint4*)(&Alds[nl * S + c]) = o0;
    }
  }
  __syncthreads();

  // MFMA phase
  const int m = lane & 15;
  const int q = lane >> 4;
  f32x4 acc[4];
#pragma unroll
  for (int t = 0; t < 4; ++t) acc[t] = (f32x4){0.f, 0.f, 0.f, 0.f};

  const unsigned short* arow = &Alds[m * S + (q << 3)];
  const int nb = (wave << 6) + m;
  const int kblocks = D >> 5;
  for (int kb = 0; kb < kblocks; ++kb) {
    bf16x8 af = *(const bf16x8*)(arow + (kb << 5));
    const unsigned short* wp = Wp + (((size_t)(kb << 8) + nb) * 4 + q) * 8;
    bf16x8 b0 = *(const bf16x8*)(wp);
    bf16x8 b1 = *(const bf16x8*)(wp + 512);
    bf16x8 b2 = *(const bf16x8*)(wp + 1024);
    bf16x8 b3 = *(const bf16x8*)(wp + 1536);
    acc[0] = __builtin_amdgcn_mfma_f32_16x16x32_bf16(af, b0, acc[0], 0, 0, 0);
    acc[1] = __builtin_amdgcn_mfma_f32_16x16x32_bf16(af, b1, acc[1], 0, 0, 0);
    acc[2] = __builtin_amdgcn_mfma_f32_16x16x32_bf16(af, b2, acc[2], 0, 0, 0);
    acc[3] = __builtin_amdgcn_mfma_f32_16x16x32_bf16(af, b3, acc[3], 0, 0, 0);
  }
#pragma unroll
  for (int t = 0; t < 4; ++t) {
    int n = (wave << 6) + (t << 4) + m;
    float bv = b2f(Wb[bias_row * 256 + n]);
#pragma unroll
    for (int i = 0; i < 4; ++i) {
      int r = row0 + (q << 2) + i;
      float v = fmaxf(acc[t][i] + bv, 0.f);
      C[(size_t)r * 256 + n] = f2b(v);
    }
  }
}

// ---- plain GEMM: C(M x 256) = relu(A(M x K) @ W + b), bf16.
__global__ void gemm_relu(const unsigned short* __restrict__ A,
                          const unsigned short* __restrict__ Wp,
                          const unsigned short* __restrict__ Wb, int bias_row,
                          unsigned short* __restrict__ C, int K) {
  const int row0 = blockIdx.x << 4;
  const int lane = threadIdx.x & 63;
  const int wave = threadIdx.x >> 6;
  const int m = lane & 15;
  const int q = lane >> 4;
  f32x4 acc[4];
#pragma unroll
  for (int t = 0; t < 4; ++t) acc[t] = (f32x4){0.f, 0.f, 0.f, 0.f};

  const unsigned short* arow = A + (size_t)(row0 + m) * K + (q << 3);
  const int nb = (wave << 6) + m;
  const int kblocks = K >> 5;
  for (int kb = 0; kb < kblocks; ++kb) {
    bf16x8 af = *(const bf16x8*)(arow + (kb << 5));
    const unsigned short* wp = Wp + (((size_t)(kb << 8) + nb) * 4 + q) * 8;
    bf16x8 b0 = *(const bf16x8*)(wp);
    bf16x8 b1 = *(const bf16x8*)(wp + 512);
    bf16x8 b2 = *(const bf16x8*)(wp + 1024);
    bf16x8 b3 = *(const bf16x8*)(wp + 1536);
    acc[0] = __builtin_amdgcn_mfma_f32_16x16x32_bf16(af, b0, acc[0], 0, 0, 0);
    acc[1] = __builtin_amdgcn_mfma_f32_16x16x32_bf16(af, b1, acc[1], 0, 0, 0);
    acc[2] = __builtin_amdgcn_mfma_f32_16x16x32_bf16(af, b2, acc[2], 0, 0, 0);
    acc[3] = __builtin_amdgcn_mfma_f32_16x16x32_bf16(af, b3, acc[3], 0, 0, 0);
  }
#pragma unroll
  for (int t = 0; t < 4; ++t) {
    int n = (wave << 6) + (t << 4) + m;
    float bv = b2f(Wb[bias_row * 256 + n]);
#pragma unroll
    for (int i = 0; i < 4; ++i) {
      int r = row0 + (q << 2) + i;
      float v = fmaxf(acc[t][i] + bv, 0.f);
      C[(size_t)r * 256 + n] = f2b(v);
    }
  }
}

// ---- last GEMM with fused mean-pool accumulation (h2 never materialized).
__global__ void gemm_pool(const unsigned short* __restrict__ A,
                          const unsigned short* __restrict__ Wp,
                          const unsigned short* __restrict__ Wb, int bias_row,
                          float* __restrict__ pool32, const int* __restrict__ batch,
                          const int* __restrict__ flags, int K) {
  __shared__ int sg[16];
  const int row0 = blockIdx.x << 4;
  const int lane = threadIdx.x & 63;
  const int wave = threadIdx.x >> 6;
  if (threadIdx.x < 16) {
    int r = row0 + threadIdx.x;
    sg[threadIdx.x] = flags[1] ? batch[2 * r] : batch[r];
  }
  __syncthreads();

  const int m = lane & 15;
  const int q = lane >> 4;
  f32x4 acc[4];
#pragma unroll
  for (int t = 0; t < 4; ++t) acc[t] = (f32x4){0.f, 0.f, 0.f, 0.f};

  const unsigned short* arow = A + (size_t)(row0 + m) * K + (q << 3);
  const int nb = (wave << 6) + m;
  const int kblocks = K >> 5;
  for (int kb = 0; kb < kblocks; ++kb) {
    bf16x8 af = *(const bf16x8*)(arow + (kb << 5));
    const unsigned short* wp = Wp + (((size_t)(kb << 8) + nb) * 4 + q) * 8;
    bf16x8 b0 = *(const bf16x8*)(wp);
    bf16x8 b1 = *(const bf16x8*)(wp + 512);
    bf16x8 b2 = *(const bf16x8*)(wp + 1024);
    bf16x8 b3 = *(const bf16x8*)(wp + 1536);
    acc[0] = __builtin_amdgcn_mfma_f32_16x16x32_bf16(af, b0, acc[0], 0, 0, 0);
    acc[1] = __builtin_amdgcn_mfma_f32_16x16x32_bf16(af, b1, acc[1], 0, 0, 0);
    acc[2] = __builtin_amdgcn_mfma_f32_16x16x32_bf16(af, b2, acc[2], 0, 0, 0);
    acc[3] = __builtin_amdgcn_mfma_f32_16x16x32_bf16(af, b3, acc[3], 0, 0, 0);
  }

  int uniform = (sg[0] == sg[15]);
#pragma unroll
  for (int t = 0; t < 4; ++t) {
    int n = (wave << 6) + (t << 4) + m;
    float bv = b2f(Wb[bias_row * 256 + n]);
    float v0 = fmaxf(acc[t][0] + bv, 0.f);
    float v1 = fmaxf(acc[t][1] + bv, 0.f);
    float v2 = fmaxf(acc[t][2] + bv, 0.f);
    float v3 = fmaxf(acc[t][3] + bv, 0.f);
    if (uniform) {
      float ps = v0 + v1 + v2 + v3;
      ps += __shfl_xor(ps, 16);
      ps += __shfl_xor(ps, 32);
      if (q == 0) unsafeAtomicAdd(&pool32[sg[0] * 256 + n], ps);
    } else {
      int gp = sg[q << 2];
      float a = 0.f;
      float vv[4] = {v0, v1, v2, v3};
#pragma unroll
      for (int i = 0; i < 4; ++i) {
        int g = sg[(q << 2) + i];
        if (g != gp) { unsafeAtomicAdd(&pool32[gp * 256 + n], a); a = 0.f; gp = g; }
        a += vv[i];
      }
      unsafeAtomicAdd(&pool32[gp * 256 + n], a);
    }
  }
}

// ---- finalize: divide by segment length, dtype-aware store
__device__ __forceinline__ int lower_bound(const int* a, int n, int v, int is64) {
  int lo = 0, hi = n;
  while (lo < hi) {
    int mid = (lo + hi) >> 1;
    int bv = is64 ? a[2 * mid] : a[mid];
    if (bv < v) lo = mid + 1; else hi = mid;
  }
  return lo;
}

__global__ void pool_final(const float* __restrict__ pool32,
                           const int* __restrict__ batch,
                           void* __restrict__ out,
                           const int* __restrict__ flags) {
  __shared__ int sh[2];
  int g = blockIdx.x;
  int is64 = flags[1];
  if (threadIdx.x == 0) sh[0] = lower_bound(batch, N_NODES, g, is64);
  if (threadIdx.x == 1) sh[1] = lower_bound(batch, N_NODES, g + 1, is64);
  __syncthreads();
  int c = threadIdx.x;
  float res = pool32[g * 256 + c] / fmaxf((float)(sh[1] - sh[0]), 1.0f);
  if (flags[0]) ((unsigned short*)out)[(size_t)g * 256 + c] = f2b(res);
  else          ((float*)out)[(size_t)g * 256 + c] = res;
}

extern "C" void kernel_launch(void* const* d_in, const int* in_sizes, int n_in,
                              void* d_out, int out_size, void* d_ws, size_t ws_size,
                              hipStream_t stream) {
  const void* x    = d_in[0];
  const int*  ei   = (const int*)d_in[1];
  const int*  batch= (const int*)d_in[2];

  char* ws = (char*)d_ws;
  int*            flags = (int*)(ws + OFF_FLAGS);
  unsigned short* Wb    = (unsigned short*)(ws + OFF_WB);
  unsigned short* Wp0   = (unsigned short*)(ws + OFF_WP0);
  unsigned short* Wp1   = (unsigned short*)(ws + OFF_WP1);
  unsigned short* Wp2   = (unsigned short*)(ws + OFF_WP2);
  unsigned short* Wp3   = (unsigned short*)(ws + OFF_WP3);
  int*            cnts  = (int*)(ws + OFF_CNT);
  int*            rowp  = (int*)(ws + OFF_ROWPTR);
  int*            curs  = (int*)(ws + OFF_CURSOR);
  unsigned short* ssrc  = (unsigned short*)(ws + OFF_SSRC);
  unsigned short* A     = (unsigned short*)(ws + OFF_A);
  unsigned short* B     = (unsigned short*)(ws + OFF_B);
  unsigned short* C     = (unsigned short*)(ws + OFF_C);
  float*          pool32= (float*)(ws + OFF_POOL32);
  int*            bsum  = (int*)(ws + OFF_BSUM);
  int*            boff  = (int*)(ws + OFF_BOFF);

  detect_zero<<<197, 256, 0, stream>>>((const unsigned int*)x, (const unsigned int*)ei,
                                       flags, cnts, pool32);
  prep_kernel<<<PB_TOTAL, 256, 0, stream>>>(x, ei,
                                            d_in[3], d_in[5], d_in[7], d_in[9],
                                            d_in[4], d_in[6], d_in[8], d_in[10],
                                            A, cnts, Wp0, Wp1, Wp2, Wp3, Wb, flags);
  scan_blocks<<<SCAN_BLOCKS, 256, 0, stream>>>(cnts, rowp, bsum);
  scan_sums<<<1, 256, 0, stream>>>(bsum, boff);
  scan_add<<<SCAN_BLOCKS, 256, 0, stream>>>(rowp, curs, boff);
  fill_kernel<<<3125, 256, 0, stream>>>(ei, curs, ssrc, flags);

  // layer 1 (feat = x directly when bf16, else converted A)
  fused_gather_gemm<<<3125, 256, 0, stream>>>(A, (const unsigned short*)x, rowp, ssrc,
                                              Wp0, Wb, 0, C, 128, flags);   // t -> C
  gemm_relu<<<3125, 256, 0, stream>>>(C, Wp1, Wb, 1, B, 256);               // h1 -> B

  // layer 2
  fused_gather_gemm<<<3125, 256, 0, stream>>>(B, B, rowp, ssrc,
                                              Wp2, Wb, 2, C, 256, flags);   // t2 -> C
  gemm_pool<<<3125, 256, 0, stream>>>(C, Wp3, Wb, 3, pool32, batch, flags, 256);

  pool_final<<<N_GRAPHS, 256, 0, stream>>>(pool32, batch, d_out, flags);
}

// Round 8
// 383.697 us; speedup vs baseline: 11.7330x; 1.0066x over previous
//
#include <hip/hip_runtime.h>

// ---------------------------------------------------------------------------
// GIN (2 layers) + global mean pool, MI355X (gfx950).
// R8: degree-balanced node permutation for the fused gather-GEMMs.
// Wave gathers 4 nodes in 16-lane subgroups -> time = max(deg of 4); sorting
// nodes by degree makes tiles degree-uniform (divergence waste ~0; measured
// gap 2.67 vs 3.3 TB/s == E[max4]/mean for Poisson16). Perm built with
// LDS-aggregated bucket histogram; scan_sums+scan_add merged.
//
// Pipeline (11 dispatches):
//   detect+zero | prep(conv+hist+packs+bias) | scan_blocks(+deg hist)
//   deg_scan | scan_fix(rowptr/cursor + perm) | fill
//   fused(x/A,128,Wp0,perm) -> t(C) | gemm(C,Wp1) -> h1(B)
//   fused(B,256,Wp2,perm) -> t2(C) | gemm_pool(C,Wp3) | pool_final
// ---------------------------------------------------------------------------

typedef __bf16 bf16x8 __attribute__((ext_vector_type(8)));
typedef float f32x4 __attribute__((ext_vector_type(4)));

#define N_NODES 50000
#define N_EDGES 800000
#define N_GRAPHS 64
#define SCAN_BLOCKS 196

// prep kernel block ranges
#define PB_HIST0 3125
#define PB_P0    6250
#define PB_P1    6378
#define PB_P2    6634
#define PB_P3    6890
#define PB_BIAS  7146
#define PB_TOTAL 7150

#define OFF_FLAGS  0ull
#define OFF_WB     64ull
#define OFF_WP0    4096ull
#define OFF_WP1    (OFF_WP0 + 65536ull)
#define OFF_WP2    (OFF_WP1 + 131072ull)
#define OFF_WP3    (OFF_WP2 + 131072ull)
#define OFF_CNT    462848ull
#define OFF_ROWPTR 662864ull
#define OFF_CURSOR 862880ull
#define OFF_SSRC   1062912ull
#define OFF_A      2662912ull               // 12.8 MB
#define OFF_B      15462912ull              // 25.6 MB
#define OFF_C      41062912ull              // 25.6 MB
#define OFF_POOL32 66662912ull              // 64 KB
#define OFF_BSUM   66728448ull
#define OFF_DCNT   66730496ull              // 256 ints
#define OFF_DCUR   66731520ull              // 256 ints
#define OFF_PERM   66732544ull              // 200 KB (end ~66.93 MB)

__device__ __forceinline__ float b2f(unsigned short u) {
  union { unsigned int i; float f; } v; v.i = ((unsigned int)u) << 16; return v.f;
}
__device__ __forceinline__ float b2f_lo(unsigned int u) {
  union { unsigned int i; float f; } v; v.i = u << 16; return v.f;
}
__device__ __forceinline__ float b2f_hi(unsigned int u) {
  union { unsigned int i; float f; } v; v.i = u & 0xffff0000u; return v.f;
}
__device__ __forceinline__ unsigned short f2b(float f) {
  union { unsigned int i; float f; } v; v.f = f;
  unsigned int r = v.i + 0x7fffu + ((v.i >> 16) & 1u);
  return (unsigned short)(r >> 16);
}

// ---- block 0: dtype detect; blocks 1..196: zero counts/pool32/dcnt
__global__ void detect_zero(const unsigned int* __restrict__ xw,
                            const unsigned int* __restrict__ eiw,
                            int* __restrict__ flags,
                            int* __restrict__ counts, float* __restrict__ pool32,
                            int* __restrict__ dcnt) {
  if (blockIdx.x == 0) {
    __shared__ int s_f[256], s_i[256];
    int t = threadIdx.x;
    int fh = 0, iz = 0;
    for (int i = t; i < 1024; i += 256) {
      unsigned int e = (xw[i] >> 7) & 0xFFu;
      fh += (e >= 115u && e <= 130u) ? 1 : 0;
      iz += (eiw[2 * i + 1] == 0u) ? 1 : 0;
    }
    s_f[t] = fh; s_i[t] = iz;
    __syncthreads();
    for (int s = 128; s > 0; s >>= 1) {
      if (t < s) { s_f[t] += s_f[t + s]; s_i[t] += s_i[t + s]; }
      __syncthreads();
    }
    if (t == 0) { flags[0] = s_f[0] > 512 ? 1 : 0; flags[1] = s_i[0] > 512 ? 1 : 0; }
  } else {
    int i = (blockIdx.x - 1) * 256 + threadIdx.x;
    if (i < N_NODES) counts[i] = 0;
    if (i < N_GRAPHS * 256) pool32[i] = 0.f;
    if (i < 256) dcnt[i] = 0;
  }
}

// ---- prep: conv(f32 only) + edge-dst hist + 4 weight packs + bias
__device__ __forceinline__ void pack_w_elem(const void* W, unsigned short* Wp,
                                            int e, int isb) {
  int n = e & 255;
  int krow = e >> 8;
  int kb = krow >> 5, r = krow & 31;
  int q = r >> 3, j = r & 7;
  size_t out = ((((size_t)(kb << 8) + n) << 2) + q) * 8 + j;
  Wp[out] = isb ? ((const unsigned short*)W)[e] : f2b(((const float*)W)[e]);
}

__global__ void prep_kernel(const void* __restrict__ x, const int* __restrict__ ei,
                            const void* W0, const void* W1, const void* W2, const void* W3,
                            const void* b0, const void* b1, const void* b2, const void* b3,
                            unsigned short* __restrict__ A,
                            int* __restrict__ counts,
                            unsigned short* __restrict__ Wp0, unsigned short* __restrict__ Wp1,
                            unsigned short* __restrict__ Wp2, unsigned short* __restrict__ Wp3,
                            unsigned short* __restrict__ Wb,
                            const int* __restrict__ flags) {
  int b = blockIdx.x, t = threadIdx.x;
  int isb = flags[0];
  if (b < PB_HIST0) {
    if (!isb) {
      int i = b * 256 + t;
      const float4* f = (const float4*)x;
      float4 a = f[2 * i], c = f[2 * i + 1];
      ushort4 o0; o0.x = f2b(a.x); o0.y = f2b(a.y); o0.z = f2b(a.z); o0.w = f2b(a.w);
      ushort4 o1; o1.x = f2b(c.x); o1.y = f2b(c.y); o1.z = f2b(c.z); o1.w = f2b(c.w);
      ((ushort4*)A)[2 * i] = o0;
      ((ushort4*)A)[2 * i + 1] = o1;
    }
  } else if (b < PB_P0) {
    int e = (b - PB_HIST0) * 256 + t;
    int dst = flags[1] ? ei[2 * (N_EDGES + e)] : ei[N_EDGES + e];
    atomicAdd(&counts[dst], 1);
  } else if (b < PB_P1) {
    pack_w_elem(W0, Wp0, (b - PB_P0) * 256 + t, isb);
  } else if (b < PB_P2) {
    pack_w_elem(W1, Wp1, (b - PB_P1) * 256 + t, isb);
  } else if (b < PB_P3) {
    pack_w_elem(W2, Wp2, (b - PB_P2) * 256 + t, isb);
  } else if (b < PB_BIAS) {
    pack_w_elem(W3, Wp3, (b - PB_P3) * 256 + t, isb);
  } else {
    int i = (b - PB_BIAS) * 256 + t;
    const void* p = (i < 256) ? b0 : (i < 512) ? b1 : (i < 768) ? b2 : b3;
    int n = i & 255;
    Wb[i] = isb ? ((const unsigned short*)p)[n] : f2b(((const float*)p)[n]);
  }
}

// ---- scan stage 1: chunk-local scan + chunk sums + LDS degree histogram
__global__ void scan_blocks(const int* __restrict__ counts,
                            int* __restrict__ rowptr, int* __restrict__ bsum,
                            int* __restrict__ dcnt) {
  __shared__ int sd[256], lh[256];
  int t = threadIdx.x;
  int i = blockIdx.x * 256 + t;
  int v = (i < N_NODES) ? counts[i] : 0;
  sd[t] = v;
  lh[t] = 0;
  __syncthreads();
  if (i < N_NODES) atomicAdd(&lh[v > 255 ? 255 : v], 1);
  __syncthreads();
  if (lh[t] > 0) atomicAdd(&dcnt[t], lh[t]);
  for (int off = 1; off < 256; off <<= 1) {
    int u = (t >= off) ? sd[t - off] : 0;
    __syncthreads();
    sd[t] += u;
    __syncthreads();
  }
  if (i < N_NODES) rowptr[i] = sd[t] - v;
  if (t == 255) bsum[blockIdx.x] = sd[255];
}

// ---- scan stage 2: exclusive scan of the 256 degree buckets
__global__ void deg_scan(const int* __restrict__ dcnt, int* __restrict__ dcur) {
  __shared__ int sd[256];
  int t = threadIdx.x;
  int v = dcnt[t];
  sd[t] = v;
  __syncthreads();
  for (int off = 1; off < 256; off <<= 1) {
    int u = (t >= off) ? sd[t - off] : 0;
    __syncthreads();
    sd[t] += u;
    __syncthreads();
  }
  dcur[t] = sd[t] - v;
}

// ---- scan stage 3: apply chunk offsets (redundant bsum scan per block),
// mirror to cursor, and fill degree-sorted perm (block-aggregated ranks).
__global__ void scan_fix(int* __restrict__ rowptr, int* __restrict__ cursor,
                         const int* __restrict__ bsum, const int* __restrict__ counts,
                         int* __restrict__ dcur, int* __restrict__ perm) {
  __shared__ int sb[256], base[256], lc[256];
  int t = threadIdx.x;
  sb[t] = (t < SCAN_BLOCKS) ? bsum[t] : 0;
  lc[t] = 0;
  __syncthreads();
  for (int off = 1; off < 256; off <<= 1) {
    int u = (t >= off) ? sb[t - off] : 0;
    __syncthreads();
    sb[t] += u;
    __syncthreads();
  }
  int boffv = (blockIdx.x > 0) ? sb[blockIdx.x - 1] : 0;
  int i = blockIdx.x * 256 + t;
  int d = 0;
  if (i < N_NODES) {
    int v = rowptr[i] + boffv;
    rowptr[i] = v;
    cursor[i] = v;
    int c = counts[i];
    d = c > 255 ? 255 : c;
    atomicAdd(&lc[d], 1);
  }
  if (i == 0) rowptr[N_NODES] = N_EDGES;
  __syncthreads();
  int cnt = lc[t];
  base[t] = (cnt > 0) ? atomicAdd(&dcur[t], cnt) : 0;
  __syncthreads();
  lc[t] = 0;
  __syncthreads();
  if (i < N_NODES) {
    int r = atomicAdd(&lc[d], 1);
    perm[base[d] + r] = i;
  }
}

__global__ void fill_kernel(const int* __restrict__ ei, int* __restrict__ cursor,
                            unsigned short* __restrict__ ssrc,
                            const int* __restrict__ flags) {
  int e = blockIdx.x * blockDim.x + threadIdx.x;
  if (e >= N_EDGES) return;
  int is64 = flags[1];
  int src = is64 ? ei[2 * e] : ei[e];
  int dst = is64 ? ei[2 * (N_EDGES + e)] : ei[N_EDGES + e];
  int pos = atomicAdd(&cursor[dst], 1);
  ssrc[pos] = (unsigned short)src;
}

// ---- fused gather + GEMM over degree-sorted node tiles.
// Block handles nodes perm[16b..16b+16): gather (16-lane subgroup/node,
// degree-uniform -> no divergence), LDS A-tile, MFMA, scatter C rows by perm.
__global__ void fused_gather_gemm(const unsigned short* __restrict__ featCanon,
                                  const unsigned short* __restrict__ featRaw,
                                  const int* __restrict__ rowptr,
                                  const unsigned short* __restrict__ ssrc,
                                  const int* __restrict__ perm,
                                  const unsigned short* __restrict__ Wp,
                                  const unsigned short* __restrict__ Wb, int bias_row,
                                  unsigned short* __restrict__ C, int D,
                                  const int* __restrict__ flags) {
  __shared__ __align__(16) unsigned short Alds[16 * 264];
  __shared__ int sp[16];
  const int S = D + 8;
  const int row0 = blockIdx.x << 4;
  const int lane = threadIdx.x & 63;
  const int wave = threadIdx.x >> 6;
  const unsigned short* feat = flags[0] ? featRaw : featCanon;
  if (threadIdx.x < 16) sp[threadIdx.x] = perm[row0 + threadIdx.x];
  __syncthreads();

  {  // gather phase
    int sub = lane >> 4;
    int l = lane & 15;
    int nl = (wave << 2) + sub;
    int node = sp[nl];
    int beg = rowptr[node], end = rowptr[node + 1];
    int c = l << 3;
    if (D == 256) {
      const unsigned short* spt = feat + (size_t)node * 256 + c;
      uint4 sv0 = *(const uint4*)spt;
      uint4 sv1 = *(const uint4*)(spt + 128);
      float a0 = b2f_lo(sv0.x), a1 = b2f_hi(sv0.x), a2 = b2f_lo(sv0.y), a3 = b2f_hi(sv0.y);
      float a4 = b2f_lo(sv0.z), a5 = b2f_hi(sv0.z), a6 = b2f_lo(sv0.w), a7 = b2f_hi(sv0.w);
      float a8 = b2f_lo(sv1.x), a9 = b2f_hi(sv1.x), aA = b2f_lo(sv1.y), aB = b2f_hi(sv1.y);
      float aC = b2f_lo(sv1.z), aD = b2f_hi(sv1.z), aE = b2f_lo(sv1.w), aF = b2f_hi(sv1.w);
      int i = beg;
      for (; i + 1 < end; i += 2) {
        int s0 = ssrc[i], s1 = ssrc[i + 1];
        const unsigned short* p0 = feat + (size_t)s0 * 256 + c;
        const unsigned short* p1 = feat + (size_t)s1 * 256 + c;
        uint4 v00 = *(const uint4*)p0;
        uint4 v01 = *(const uint4*)(p0 + 128);
        uint4 v10 = *(const uint4*)p1;
        uint4 v11 = *(const uint4*)(p1 + 128);
        a0 += b2f_lo(v00.x); a1 += b2f_hi(v00.x); a2 += b2f_lo(v00.y); a3 += b2f_hi(v00.y);
        a4 += b2f_lo(v00.z); a5 += b2f_hi(v00.z); a6 += b2f_lo(v00.w); a7 += b2f_hi(v00.w);
        a8 += b2f_lo(v01.x); a9 += b2f_hi(v01.x); aA += b2f_lo(v01.y); aB += b2f_hi(v01.y);
        aC += b2f_lo(v01.z); aD += b2f_hi(v01.z); aE += b2f_lo(v01.w); aF += b2f_hi(v01.w);
        a0 += b2f_lo(v10.x); a1 += b2f_hi(v10.x); a2 += b2f_lo(v10.y); a3 += b2f_hi(v10.y);
        a4 += b2f_lo(v10.z); a5 += b2f_hi(v10.z); a6 += b2f_lo(v10.w); a7 += b2f_hi(v10.w);
        a8 += b2f_lo(v11.x); a9 += b2f_hi(v11.x); aA += b2f_lo(v11.y); aB += b2f_hi(v11.y);
        aC += b2f_lo(v11.z); aD += b2f_hi(v11.z); aE += b2f_lo(v11.w); aF += b2f_hi(v11.w);
      }
      if (i < end) {
        const unsigned short* p0 = feat + (size_t)ssrc[i] * 256 + c;
        uint4 v00 = *(const uint4*)p0;
        uint4 v01 = *(const uint4*)(p0 + 128);
        a0 += b2f_lo(v00.x); a1 += b2f_hi(v00.x); a2 += b2f_lo(v00.y); a3 += b2f_hi(v00.y);
        a4 += b2f_lo(v00.z); a5 += b2f_hi(v00.z); a6 += b2f_lo(v00.w); a7 += b2f_hi(v00.w);
        a8 += b2f_lo(v01.x); a9 += b2f_hi(v01.x); aA += b2f_lo(v01.y); aB += b2f_hi(v01.y);
        aC += b2f_lo(v01.z); aD += b2f_hi(v01.z); aE += b2f_lo(v01.w); aF += b2f_hi(v01.w);
      }
      uint4 o0, o1;
      o0.x = ((unsigned int)f2b(a1) << 16) | f2b(a0);
      o0.y = ((unsigned int)f2b(a3) << 16) | f2b(a2);
      o0.z = ((unsigned int)f2b(a5) << 16) | f2b(a4);
      o0.w = ((unsigned int)f2b(a7) << 16) | f2b(a6);
      o1.x = ((unsigned int)f2b(a9) << 16) | f2b(a8);
      o1.y = ((unsigned int)f2b(aB) << 16) | f2b(aA);
      o1.z = ((unsigned int)f2b(aD) << 16) | f2b(aC);
      o1.w = ((unsigned int)f2b(aF) << 16) | f2b(aE);
      *(uint4*)(&Alds[nl * S + c]) = o0;
      *(uint4*)(&Alds[nl * S + c + 128]) = o1;
    } else {  // D == 128
      const unsigned short* spt = feat + (size_t)node * 128 + c;
      uint4 sv0 = *(const uint4*)spt;
      float a0 = b2f_lo(sv0.x), a1 = b2f_hi(sv0.x), a2 = b2f_lo(sv0.y), a3 = b2f_hi(sv0.y);
      float a4 = b2f_lo(sv0.z), a5 = b2f_hi(sv0.z), a6 = b2f_lo(sv0.w), a7 = b2f_hi(sv0.w);
      int i = beg;
      for (; i + 1 < end; i += 2) {
        int s0 = ssrc[i], s1 = ssrc[i + 1];
        uint4 v0 = *(const uint4*)(feat + (size_t)s0 * 128 + c);
        uint4 v1 = *(const uint4*)(feat + (size_t)s1 * 128 + c);
        a0 += b2f_lo(v0.x); a1 += b2f_hi(v0.x); a2 += b2f_lo(v0.y); a3 += b2f_hi(v0.y);
        a4 += b2f_lo(v0.z); a5 += b2f_hi(v0.z); a6 += b2f_lo(v0.w); a7 += b2f_hi(v0.w);
        a0 += b2f_lo(v1.x); a1 += b2f_hi(v1.x); a2 += b2f_lo(v1.y); a3 += b2f_hi(v1.y);
        a4 += b2f_lo(v1.z); a5 += b2f_hi(v1.z); a6 += b2f_lo(v1.w); a7 += b2f_hi(v1.w);
      }
      if (i < end) {
        uint4 v0 = *(const uint4*)(feat + (size_t)ssrc[i] * 128 + c);
        a0 += b2f_lo(v0.x); a1 += b2f_hi(v0.x); a2 += b2f_lo(v0.y); a3 += b2f_hi(v0.y);
        a4 += b2f_lo(v0.z); a5 += b2f_hi(v0.z); a6 += b2f_lo(v0.w); a7 += b2f_hi(v0.w);
      }
      uint4 o0;
      o0.x = ((unsigned int)f2b(a1) << 16) | f2b(a0);
      o0.y = ((unsigned int)f2b(a3) << 16) | f2b(a2);
      o0.z = ((unsigned int)f2b(a5) << 16) | f2b(a4);
      o0.w = ((unsigned int)f2b(a7) << 16) | f2b(a6);
      *(uint4*)(&Alds[nl * S + c]) = o0;
    }
  }
  __syncthreads();

  // MFMA phase
  const int m = lane & 15;
  const int q = lane >> 4;
  f32x4 acc[4];
#pragma unroll
  for (int t = 0; t < 4; ++t) acc[t] = (f32x4){0.f, 0.f, 0.f, 0.f};

  const unsigned short* arow = &Alds[m * S + (q << 3)];
  const int nb = (wave << 6) + m;
  const int kblocks = D >> 5;
  for (int kb = 0; kb < kblocks; ++kb) {
    bf16x8 af = *(const bf16x8*)(arow + (kb << 5));
    const unsigned short* wp = Wp + (((size_t)(kb << 8) + nb) * 4 + q) * 8;
    bf16x8 b0 = *(const bf16x8*)(wp);
    bf16x8 b1 = *(const bf16x8*)(wp + 512);
    bf16x8 b2 = *(const bf16x8*)(wp + 1024);
    bf16x8 b3 = *(const bf16x8*)(wp + 1536);
    acc[0] = __builtin_amdgcn_mfma_f32_16x16x32_bf16(af, b0, acc[0], 0, 0, 0);
    acc[1] = __builtin_amdgcn_mfma_f32_16x16x32_bf16(af, b1, acc[1], 0, 0, 0);
    acc[2] = __builtin_amdgcn_mfma_f32_16x16x32_bf16(af, b2, acc[2], 0, 0, 0);
    acc[3] = __builtin_amdgcn_mfma_f32_16x16x32_bf16(af, b3, acc[3], 0, 0, 0);
  }
#pragma unroll
  for (int t = 0; t < 4; ++t) {
    int n = (wave << 6) + (t << 4) + m;
    float bv = b2f(Wb[bias_row * 256 + n]);
#pragma unroll
    for (int i = 0; i < 4; ++i) {
      int r = sp[(q << 2) + i];
      float v = fmaxf(acc[t][i] + bv, 0.f);
      C[(size_t)r * 256 + n] = f2b(v);
    }
  }
}

// ---- plain GEMM: C(M x 256) = relu(A(M x K) @ W + b), bf16.
__global__ void gemm_relu(const unsigned short* __restrict__ A,
                          const unsigned short* __restrict__ Wp,
                          const unsigned short* __restrict__ Wb, int bias_row,
                          unsigned short* __restrict__ C, int K) {
  const int row0 = blockIdx.x << 4;
  const int lane = threadIdx.x & 63;
  const int wave = threadIdx.x >> 6;
  const int m = lane & 15;
  const int q = lane >> 4;
  f32x4 acc[4];
#pragma unroll
  for (int t = 0; t < 4; ++t) acc[t] = (f32x4){0.f, 0.f, 0.f, 0.f};

  const unsigned short* arow = A + (size_t)(row0 + m) * K + (q << 3);
  const int nb = (wave << 6) + m;
  const int kblocks = K >> 5;
  for (int kb = 0; kb < kblocks; ++kb) {
    bf16x8 af = *(const bf16x8*)(arow + (kb << 5));
    const unsigned short* wp = Wp + (((size_t)(kb << 8) + nb) * 4 + q) * 8;
    bf16x8 b0 = *(const bf16x8*)(wp);
    bf16x8 b1 = *(const bf16x8*)(wp + 512);
    bf16x8 b2 = *(const bf16x8*)(wp + 1024);
    bf16x8 b3 = *(const bf16x8*)(wp + 1536);
    acc[0] = __builtin_amdgcn_mfma_f32_16x16x32_bf16(af, b0, acc[0], 0, 0, 0);
    acc[1] = __builtin_amdgcn_mfma_f32_16x16x32_bf16(af, b1, acc[1], 0, 0, 0);
    acc[2] = __builtin_amdgcn_mfma_f32_16x16x32_bf16(af, b2, acc[2], 0, 0, 0);
    acc[3] = __builtin_amdgcn_mfma_f32_16x16x32_bf16(af, b3, acc[3], 0, 0, 0);
  }
#pragma unroll
  for (int t = 0; t < 4; ++t) {
    int n = (wave << 6) + (t << 4) + m;
    float bv = b2f(Wb[bias_row * 256 + n]);
#pragma unroll
    for (int i = 0; i < 4; ++i) {
      int r = row0 + (q << 2) + i;
      float v = fmaxf(acc[t][i] + bv, 0.f);
      C[(size_t)r * 256 + n] = f2b(v);
    }
  }
}

// ---- last GEMM with fused mean-pool accumulation (h2 never materialized).
__global__ void gemm_pool(const unsigned short* __restrict__ A,
                          const unsigned short* __restrict__ Wp,
                          const unsigned short* __restrict__ Wb, int bias_row,
                          float* __restrict__ pool32, const int* __restrict__ batch,
                          const int* __restrict__ flags, int K) {
  __shared__ int sg[16];
  const int row0 = blockIdx.x << 4;
  const int lane = threadIdx.x & 63;
  const int wave = threadIdx.x >> 6;
  if (threadIdx.x < 16) {
    int r = row0 + threadIdx.x;
    sg[threadIdx.x] = flags[1] ? batch[2 * r] : batch[r];
  }
  __syncthreads();

  const int m = lane & 15;
  const int q = lane >> 4;
  f32x4 acc[4];
#pragma unroll
  for (int t = 0; t < 4; ++t) acc[t] = (f32x4){0.f, 0.f, 0.f, 0.f};

  const unsigned short* arow = A + (size_t)(row0 + m) * K + (q << 3);
  const int nb = (wave << 6) + m;
  const int kblocks = K >> 5;
  for (int kb = 0; kb < kblocks; ++kb) {
    bf16x8 af = *(const bf16x8*)(arow + (kb << 5));
    const unsigned short* wp = Wp + (((size_t)(kb << 8) + nb) * 4 + q) * 8;
    bf16x8 b0 = *(const bf16x8*)(wp);
    bf16x8 b1 = *(const bf16x8*)(wp + 512);
    bf16x8 b2 = *(const bf16x8*)(wp + 1024);
    bf16x8 b3 = *(const bf16x8*)(wp + 1536);
    acc[0] = __builtin_amdgcn_mfma_f32_16x16x32_bf16(af, b0, acc[0], 0, 0, 0);
    acc[1] = __builtin_amdgcn_mfma_f32_16x16x32_bf16(af, b1, acc[1], 0, 0, 0);
    acc[2] = __builtin_amdgcn_mfma_f32_16x16x32_bf16(af, b2, acc[2], 0, 0, 0);
    acc[3] = __builtin_amdgcn_mfma_f32_16x16x32_bf16(af, b3, acc[3], 0, 0, 0);
  }

  int uniform = (sg[0] == sg[15]);
#pragma unroll
  for (int t = 0; t < 4; ++t) {
    int n = (wave << 6) + (t << 4) + m;
    float bv = b2f(Wb[bias_row * 256 + n]);
    float v0 = fmaxf(acc[t][0] + bv, 0.f);
    float v1 = fmaxf(acc[t][1] + bv, 0.f);
    float v2 = fmaxf(acc[t][2] + bv, 0.f);
    float v3 = fmaxf(acc[t][3] + bv, 0.f);
    if (uniform) {
      float ps = v0 + v1 + v2 + v3;
      ps += __shfl_xor(ps, 16);
      ps += __shfl_xor(ps, 32);
      if (q == 0) unsafeAtomicAdd(&pool32[sg[0] * 256 + n], ps);
    } else {
      int gp = sg[q << 2];
      float a = 0.f;
      float vv[4] = {v0, v1, v2, v3};
#pragma unroll
      for (int i = 0; i < 4; ++i) {
        int g = sg[(q << 2) + i];
        if (g != gp) { unsafeAtomicAdd(&pool32[gp * 256 + n], a); a = 0.f; gp = g; }
        a += vv[i];
      }
      unsafeAtomicAdd(&pool32[gp * 256 + n], a);
    }
  }
}

// ---- finalize
__device__ __forceinline__ int lower_bound(const int* a, int n, int v, int is64) {
  int lo = 0, hi = n;
  while (lo < hi) {
    int mid = (lo + hi) >> 1;
    int bv = is64 ? a[2 * mid] : a[mid];
    if (bv < v) lo = mid + 1; else hi = mid;
  }
  return lo;
}

__global__ void pool_final(const float* __restrict__ pool32,
                           const int* __restrict__ batch,
                           void* __restrict__ out,
                           const int* __restrict__ flags) {
  __shared__ int sh[2];
  int g = blockIdx.x;
  int is64 = flags[1];
  if (threadIdx.x == 0) sh[0] = lower_bound(batch, N_NODES, g, is64);
  if (threadIdx.x == 1) sh[1] = lower_bound(batch, N_NODES, g + 1, is64);
  __syncthreads();
  int c = threadIdx.x;
  float res = pool32[g * 256 + c] / fmaxf((float)(sh[1] - sh[0]), 1.0f);
  if (flags[0]) ((unsigned short*)out)[(size_t)g * 256 + c] = f2b(res);
  else          ((float*)out)[(size_t)g * 256 + c] = res;
}

extern "C" void kernel_launch(void* const* d_in, const int* in_sizes, int n_in,
                              void* d_out, int out_size, void* d_ws, size_t ws_size,
                              hipStream_t stream) {
  const void* x    = d_in[0];
  const int*  ei   = (const int*)d_in[1];
  const int*  batch= (const int*)d_in[2];

  char* ws = (char*)d_ws;
  int*            flags = (int*)(ws + OFF_FLAGS);
  unsigned short* Wb    = (unsigned short*)(ws + OFF_WB);
  unsigned short* Wp0   = (unsigned short*)(ws + OFF_WP0);
  unsigned short* Wp1   = (unsigned short*)(ws + OFF_WP1);
  unsigned short* Wp2   = (unsigned short*)(ws + OFF_WP2);
  unsigned short* Wp3   = (unsigned short*)(ws + OFF_WP3);
  int*            cnts  = (int*)(ws + OFF_CNT);
  int*            rowp  = (int*)(ws + OFF_ROWPTR);
  int*            curs  = (int*)(ws + OFF_CURSOR);
  unsigned short* ssrc  = (unsigned short*)(ws + OFF_SSRC);
  unsigned short* A     = (unsigned short*)(ws + OFF_A);
  unsigned short* B     = (unsigned short*)(ws + OFF_B);
  unsigned short* C     = (unsigned short*)(ws + OFF_C);
  float*          pool32= (float*)(ws + OFF_POOL32);
  int*            bsum  = (int*)(ws + OFF_BSUM);
  int*            dcnt  = (int*)(ws + OFF_DCNT);
  int*            dcur  = (int*)(ws + OFF_DCUR);
  int*            perm  = (int*)(ws + OFF_PERM);

  detect_zero<<<197, 256, 0, stream>>>((const unsigned int*)x, (const unsigned int*)ei,
                                       flags, cnts, pool32, dcnt);
  prep_kernel<<<PB_TOTAL, 256, 0, stream>>>(x, ei,
                                            d_in[3], d_in[5], d_in[7], d_in[9],
                                            d_in[4], d_in[6], d_in[8], d_in[10],
                                            A, cnts, Wp0, Wp1, Wp2, Wp3, Wb, flags);
  scan_blocks<<<SCAN_BLOCKS, 256, 0, stream>>>(cnts, rowp, bsum, dcnt);
  deg_scan<<<1, 256, 0, stream>>>(dcnt, dcur);
  scan_fix<<<SCAN_BLOCKS, 256, 0, stream>>>(rowp, curs, bsum, cnts, dcur, perm);
  fill_kernel<<<3125, 256, 0, stream>>>(ei, curs, ssrc, flags);

  // layer 1 (feat = x directly when bf16, else converted A)
  fused_gather_gemm<<<3125, 256, 0, stream>>>(A, (const unsigned short*)x, rowp, ssrc,
                                              perm, Wp0, Wb, 0, C, 128, flags);
  gemm_relu<<<3125, 256, 0, stream>>>(C, Wp1, Wb, 1, B, 256);

  // layer 2
  fused_gather_gemm<<<3125, 256, 0, stream>>>(B, B, rowp, ssrc,
                                              perm, Wp2, Wb, 2, C, 256, flags);
  gemm_pool<<<3125, 256, 0, stream>>>(C, Wp3, Wb, 3, pool32, batch, flags, 256);

  pool_final<<<N_GRAPHS, 256, 0, stream>>>(pool32, batch, d_out, flags);
}

// Round 9
// 378.250 us; speedup vs baseline: 11.9019x; 1.0144x over previous
//
#include <hip/hip_runtime.h>

// ---------------------------------------------------------------------------
// GIN (2 layers) + global mean pool, MI355X (gfx950).
// R9: 4-edge unroll in fused gathers (2x MLP; latency-bound at VALUBusy 21%),
// 8x replicated pool32 accumulator (800k atomics -> 16k addrs was ~50-way
// contention), deg_scan folded into scan_fix. 10 dispatches.
// ---------------------------------------------------------------------------

typedef __bf16 bf16x8 __attribute__((ext_vector_type(8)));
typedef float f32x4 __attribute__((ext_vector_type(4)));

#define N_NODES 50000
#define N_EDGES 800000
#define N_GRAPHS 64
#define SCAN_BLOCKS 196
#define NREP 8

// prep kernel block ranges
#define PB_HIST0 3125
#define PB_P0    6250
#define PB_P1    6378
#define PB_P2    6634
#define PB_P3    6890
#define PB_BIAS  7146
#define PB_TOTAL 7150

#define OFF_FLAGS  0ull
#define OFF_WB     64ull
#define OFF_WP0    4096ull
#define OFF_WP1    (OFF_WP0 + 65536ull)
#define OFF_WP2    (OFF_WP1 + 131072ull)
#define OFF_WP3    (OFF_WP2 + 131072ull)
#define OFF_CNT    462848ull
#define OFF_ROWPTR 662864ull
#define OFF_CURSOR 862880ull
#define OFF_SSRC   1062912ull
#define OFF_A      2662912ull               // 12.8 MB
#define OFF_B      15462912ull              // 25.6 MB
#define OFF_C      41062912ull              // 25.6 MB
#define OFF_POOL32 66662912ull              // 512 KB (8 replicas x 64 x 256 f32)
#define OFF_BSUM   67187200ull
#define OFF_DCNT   67189248ull
#define OFF_DCUR   67190272ull
#define OFF_PERM   67191296ull              // 200 KB (end ~67.4 MB)

__device__ __forceinline__ float b2f(unsigned short u) {
  union { unsigned int i; float f; } v; v.i = ((unsigned int)u) << 16; return v.f;
}
__device__ __forceinline__ float b2f_lo(unsigned int u) {
  union { unsigned int i; float f; } v; v.i = u << 16; return v.f;
}
__device__ __forceinline__ float b2f_hi(unsigned int u) {
  union { unsigned int i; float f; } v; v.i = u & 0xffff0000u; return v.f;
}
__device__ __forceinline__ unsigned short f2b(float f) {
  union { unsigned int i; float f; } v; v.f = f;
  unsigned int r = v.i + 0x7fffu + ((v.i >> 16) & 1u);
  return (unsigned short)(r >> 16);
}
__device__ __forceinline__ unsigned int pk2(float hi, float lo) {
  return ((unsigned int)f2b(hi) << 16) | f2b(lo);
}
__device__ __forceinline__ void acc8(float* a, uint4 v) {
  a[0] += b2f_lo(v.x); a[1] += b2f_hi(v.x);
  a[2] += b2f_lo(v.y); a[3] += b2f_hi(v.y);
  a[4] += b2f_lo(v.z); a[5] += b2f_hi(v.z);
  a[6] += b2f_lo(v.w); a[7] += b2f_hi(v.w);
}

// ---- block 0: dtype detect; blocks 1..512: zero counts/pool32/dcnt/dcur
__global__ void detect_zero(const unsigned int* __restrict__ xw,
                            const unsigned int* __restrict__ eiw,
                            int* __restrict__ flags,
                            int* __restrict__ counts, float* __restrict__ pool32,
                            int* __restrict__ dcnt, int* __restrict__ dcur) {
  if (blockIdx.x == 0) {
    __shared__ int s_f[256], s_i[256];
    int t = threadIdx.x;
    int fh = 0, iz = 0;
    for (int i = t; i < 1024; i += 256) {
      unsigned int e = (xw[i] >> 7) & 0xFFu;
      fh += (e >= 115u && e <= 130u) ? 1 : 0;
      iz += (eiw[2 * i + 1] == 0u) ? 1 : 0;
    }
    s_f[t] = fh; s_i[t] = iz;
    __syncthreads();
    for (int s = 128; s > 0; s >>= 1) {
      if (t < s) { s_f[t] += s_f[t + s]; s_i[t] += s_i[t + s]; }
      __syncthreads();
    }
    if (t == 0) { flags[0] = s_f[0] > 512 ? 1 : 0; flags[1] = s_i[0] > 512 ? 1 : 0; }
  } else {
    int i = (blockIdx.x - 1) * 256 + threadIdx.x;
    if (i < N_NODES) counts[i] = 0;
    if (i < NREP * N_GRAPHS * 256) pool32[i] = 0.f;
    if (i < 256) { dcnt[i] = 0; dcur[i] = 0; }
  }
}

// ---- prep: conv(f32 only) + edge-dst hist + 4 weight packs + bias
__device__ __forceinline__ void pack_w_elem(const void* W, unsigned short* Wp,
                                            int e, int isb) {
  int n = e & 255;
  int krow = e >> 8;
  int kb = krow >> 5, r = krow & 31;
  int q = r >> 3, j = r & 7;
  size_t out = ((((size_t)(kb << 8) + n) << 2) + q) * 8 + j;
  Wp[out] = isb ? ((const unsigned short*)W)[e] : f2b(((const float*)W)[e]);
}

__global__ void prep_kernel(const void* __restrict__ x, const int* __restrict__ ei,
                            const void* W0, const void* W1, const void* W2, const void* W3,
                            const void* b0, const void* b1, const void* b2, const void* b3,
                            unsigned short* __restrict__ A,
                            int* __restrict__ counts,
                            unsigned short* __restrict__ Wp0, unsigned short* __restrict__ Wp1,
                            unsigned short* __restrict__ Wp2, unsigned short* __restrict__ Wp3,
                            unsigned short* __restrict__ Wb,
                            const int* __restrict__ flags) {
  int b = blockIdx.x, t = threadIdx.x;
  int isb = flags[0];
  if (b < PB_HIST0) {
    if (!isb) {
      int i = b * 256 + t;
      const float4* f = (const float4*)x;
      float4 a = f[2 * i], c = f[2 * i + 1];
      ushort4 o0; o0.x = f2b(a.x); o0.y = f2b(a.y); o0.z = f2b(a.z); o0.w = f2b(a.w);
      ushort4 o1; o1.x = f2b(c.x); o1.y = f2b(c.y); o1.z = f2b(c.z); o1.w = f2b(c.w);
      ((ushort4*)A)[2 * i] = o0;
      ((ushort4*)A)[2 * i + 1] = o1;
    }
  } else if (b < PB_P0) {
    int e = (b - PB_HIST0) * 256 + t;
    int dst = flags[1] ? ei[2 * (N_EDGES + e)] : ei[N_EDGES + e];
    atomicAdd(&counts[dst], 1);
  } else if (b < PB_P1) {
    pack_w_elem(W0, Wp0, (b - PB_P0) * 256 + t, isb);
  } else if (b < PB_P2) {
    pack_w_elem(W1, Wp1, (b - PB_P1) * 256 + t, isb);
  } else if (b < PB_P3) {
    pack_w_elem(W2, Wp2, (b - PB_P2) * 256 + t, isb);
  } else if (b < PB_BIAS) {
    pack_w_elem(W3, Wp3, (b - PB_P3) * 256 + t, isb);
  } else {
    int i = (b - PB_BIAS) * 256 + t;
    const void* p = (i < 256) ? b0 : (i < 512) ? b1 : (i < 768) ? b2 : b3;
    int n = i & 255;
    Wb[i] = isb ? ((const unsigned short*)p)[n] : f2b(((const float*)p)[n]);
  }
}

// ---- scan stage 1: chunk-local scan + chunk sums + LDS degree histogram
__global__ void scan_blocks(const int* __restrict__ counts,
                            int* __restrict__ rowptr, int* __restrict__ bsum,
                            int* __restrict__ dcnt) {
  __shared__ int sd[256], lh[256];
  int t = threadIdx.x;
  int i = blockIdx.x * 256 + t;
  int v = (i < N_NODES) ? counts[i] : 0;
  sd[t] = v;
  lh[t] = 0;
  __syncthreads();
  if (i < N_NODES) atomicAdd(&lh[v > 255 ? 255 : v], 1);
  __syncthreads();
  if (lh[t] > 0) atomicAdd(&dcnt[t], lh[t]);
  for (int off = 1; off < 256; off <<= 1) {
    int u = (t >= off) ? sd[t - off] : 0;
    __syncthreads();
    sd[t] += u;
    __syncthreads();
  }
  if (i < N_NODES) rowptr[i] = sd[t] - v;
  if (t == 255) bsum[blockIdx.x] = sd[255];
}

// ---- scan stage 2: apply chunk offsets (redundant per-block scans of bsum
// and dcnt), mirror to cursor, fill degree-sorted perm via rank allocation.
__global__ void scan_fix(int* __restrict__ rowptr, int* __restrict__ cursor,
                         const int* __restrict__ bsum, const int* __restrict__ counts,
                         const int* __restrict__ dcnt, int* __restrict__ dcur,
                         int* __restrict__ perm) {
  __shared__ int sb[256], db[256], base[256], lc[256];
  int t = threadIdx.x;
  sb[t] = (t < SCAN_BLOCKS) ? bsum[t] : 0;
  db[t] = dcnt[t];
  lc[t] = 0;
  __syncthreads();
  for (int off = 1; off < 256; off <<= 1) {
    int u1 = (t >= off) ? sb[t - off] : 0;
    int u2 = (t >= off) ? db[t - off] : 0;
    __syncthreads();
    sb[t] += u1; db[t] += u2;
    __syncthreads();
  }
  db[t] -= dcnt[t];          // exclusive bucket offsets
  __syncthreads();
  int boffv = (blockIdx.x > 0) ? sb[blockIdx.x - 1] : 0;
  int i = blockIdx.x * 256 + t;
  int d = 0;
  if (i < N_NODES) {
    int v = rowptr[i] + boffv;
    rowptr[i] = v;
    cursor[i] = v;
    int c = counts[i];
    d = c > 255 ? 255 : c;
    atomicAdd(&lc[d], 1);
  }
  if (i == 0) rowptr[N_NODES] = N_EDGES;
  __syncthreads();
  int cnt = lc[t];
  base[t] = (cnt > 0) ? (db[t] + atomicAdd(&dcur[t], cnt)) : 0;
  __syncthreads();
  lc[t] = 0;
  __syncthreads();
  if (i < N_NODES) {
    int r = atomicAdd(&lc[d], 1);
    perm[base[d] + r] = i;
  }
}

__global__ void fill_kernel(const int* __restrict__ ei, int* __restrict__ cursor,
                            unsigned short* __restrict__ ssrc,
                            const int* __restrict__ flags) {
  int e = blockIdx.x * blockDim.x + threadIdx.x;
  if (e >= N_EDGES) return;
  int is64 = flags[1];
  int src = is64 ? ei[2 * e] : ei[e];
  int dst = is64 ? ei[2 * (N_EDGES + e)] : ei[N_EDGES + e];
  int pos = atomicAdd(&cursor[dst], 1);
  ssrc[pos] = (unsigned short)src;
}

// ---- fused gather + GEMM over degree-sorted node tiles; 4-edge unroll.
__global__ void fused_gather_gemm(const unsigned short* __restrict__ featCanon,
                                  const unsigned short* __restrict__ featRaw,
                                  const int* __restrict__ rowptr,
                                  const unsigned short* __restrict__ ssrc,
                                  const int* __restrict__ perm,
                                  const unsigned short* __restrict__ Wp,
                                  const unsigned short* __restrict__ Wb, int bias_row,
                                  unsigned short* __restrict__ C, int D,
                                  const int* __restrict__ flags) {
  __shared__ __align__(16) unsigned short Alds[16 * 264];
  __shared__ int sp[16];
  const int S = D + 8;
  const int row0 = blockIdx.x << 4;
  const int lane = threadIdx.x & 63;
  const int wave = threadIdx.x >> 6;
  const unsigned short* feat = flags[0] ? featRaw : featCanon;
  if (threadIdx.x < 16) sp[threadIdx.x] = perm[row0 + threadIdx.x];
  __syncthreads();

  {  // gather phase: 16-lane subgroup per node, 4-edge unroll
    int sub = lane >> 4;
    int l = lane & 15;
    int nl = (wave << 2) + sub;
    int node = sp[nl];
    int beg = rowptr[node], end = rowptr[node + 1];
    int c = l << 3;
    if (D == 256) {
      float a[16];
#pragma unroll
      for (int j = 0; j < 16; ++j) a[j] = 0.f;
      const unsigned short* spt = feat + (size_t)node * 256 + c;
      acc8(a, *(const uint4*)spt);
      acc8(a + 8, *(const uint4*)(spt + 128));
      int i = beg;
      for (; i + 3 < end; i += 4) {
        int ss[4];
#pragma unroll
        for (int e = 0; e < 4; ++e) ss[e] = ssrc[i + e];
        uint4 v[8];
#pragma unroll
        for (int e = 0; e < 4; ++e) {
          const unsigned short* p = feat + (size_t)ss[e] * 256 + c;
          v[2 * e] = *(const uint4*)p;
          v[2 * e + 1] = *(const uint4*)(p + 128);
        }
#pragma unroll
        for (int e = 0; e < 4; ++e) { acc8(a, v[2 * e]); acc8(a + 8, v[2 * e + 1]); }
      }
      for (; i < end; ++i) {
        const unsigned short* p = feat + (size_t)ssrc[i] * 256 + c;
        acc8(a, *(const uint4*)p);
        acc8(a + 8, *(const uint4*)(p + 128));
      }
      uint4 o0, o1;
      o0.x = pk2(a[1], a[0]);  o0.y = pk2(a[3], a[2]);
      o0.z = pk2(a[5], a[4]);  o0.w = pk2(a[7], a[6]);
      o1.x = pk2(a[9], a[8]);  o1.y = pk2(a[11], a[10]);
      o1.z = pk2(a[13], a[12]); o1.w = pk2(a[15], a[14]);
      *(uint4*)(&Alds[nl * S + c]) = o0;
      *(uint4*)(&Alds[nl * S + c + 128]) = o1;
    } else {  // D == 128
      float a[8];
#pragma unroll
      for (int j = 0; j < 8; ++j) a[j] = 0.f;
      acc8(a, *(const uint4*)(feat + (size_t)node * 128 + c));
      int i = beg;
      for (; i + 3 < end; i += 4) {
        int ss[4];
#pragma unroll
        for (int e = 0; e < 4; ++e) ss[e] = ssrc[i + e];
        uint4 v[4];
#pragma unroll
        for (int e = 0; e < 4; ++e)
          v[e] = *(const uint4*)(feat + (size_t)ss[e] * 128 + c);
#pragma unroll
        for (int e = 0; e < 4; ++e) acc8(a, v[e]);
      }
      for (; i < end; ++i)
        acc8(a, *(const uint4*)(feat + (size_t)ssrc[i] * 128 + c));
      uint4 o0;
      o0.x = pk2(a[1], a[0]); o0.y = pk2(a[3], a[2]);
      o0.z = pk2(a[5], a[4]); o0.w = pk2(a[7], a[6]);
      *(uint4*)(&Alds[nl * S + c]) = o0;
    }
  }
  __syncthreads();

  // MFMA phase
  const int m = lane & 15;
  const int q = lane >> 4;
  f32x4 acc[4];
#pragma unroll
  for (int t = 0; t < 4; ++t) acc[t] = (f32x4){0.f, 0.f, 0.f, 0.f};

  const unsigned short* arow = &Alds[m * S + (q << 3)];
  const int nb = (wave << 6) + m;
  const int kblocks = D >> 5;
  for (int kb = 0; kb < kblocks; ++kb) {
    bf16x8 af = *(const bf16x8*)(arow + (kb << 5));
    const unsigned short* wp = Wp + (((size_t)(kb << 8) + nb) * 4 + q) * 8;
    bf16x8 b0 = *(const bf16x8*)(wp);
    bf16x8 b1 = *(const bf16x8*)(wp + 512);
    bf16x8 b2 = *(const bf16x8*)(wp + 1024);
    bf16x8 b3 = *(const bf16x8*)(wp + 1536);
    acc[0] = __builtin_amdgcn_mfma_f32_16x16x32_bf16(af, b0, acc[0], 0, 0, 0);
    acc[1] = __builtin_amdgcn_mfma_f32_16x16x32_bf16(af, b1, acc[1], 0, 0, 0);
    acc[2] = __builtin_amdgcn_mfma_f32_16x16x32_bf16(af, b2, acc[2], 0, 0, 0);
    acc[3] = __builtin_amdgcn_mfma_f32_16x16x32_bf16(af, b3, acc[3], 0, 0, 0);
  }
#pragma unroll
  for (int t = 0; t < 4; ++t) {
    int n = (wave << 6) + (t << 4) + m;
    float bv = b2f(Wb[bias_row * 256 + n]);
#pragma unroll
    for (int i = 0; i < 4; ++i) {
      int r = sp[(q << 2) + i];
      float v = fmaxf(acc[t][i] + bv, 0.f);
      C[(size_t)r * 256 + n] = f2b(v);
    }
  }
}

// ---- plain GEMM: C(M x 256) = relu(A(M x K) @ W + b), bf16.
__global__ void gemm_relu(const unsigned short* __restrict__ A,
                          const unsigned short* __restrict__ Wp,
                          const unsigned short* __restrict__ Wb, int bias_row,
                          unsigned short* __restrict__ C, int K) {
  const int row0 = blockIdx.x << 4;
  const int lane = threadIdx.x & 63;
  const int wave = threadIdx.x >> 6;
  const int m = lane & 15;
  const int q = lane >> 4;
  f32x4 acc[4];
#pragma unroll
  for (int t = 0; t < 4; ++t) acc[t] = (f32x4){0.f, 0.f, 0.f, 0.f};

  const unsigned short* arow = A + (size_t)(row0 + m) * K + (q << 3);
  const int nb = (wave << 6) + m;
  const int kblocks = K >> 5;
  for (int kb = 0; kb < kblocks; ++kb) {
    bf16x8 af = *(const bf16x8*)(arow + (kb << 5));
    const unsigned short* wp = Wp + (((size_t)(kb << 8) + nb) * 4 + q) * 8;
    bf16x8 b0 = *(const bf16x8*)(wp);
    bf16x8 b1 = *(const bf16x8*)(wp + 512);
    bf16x8 b2 = *(const bf16x8*)(wp + 1024);
    bf16x8 b3 = *(const bf16x8*)(wp + 1536);
    acc[0] = __builtin_amdgcn_mfma_f32_16x16x32_bf16(af, b0, acc[0], 0, 0, 0);
    acc[1] = __builtin_amdgcn_mfma_f32_16x16x32_bf16(af, b1, acc[1], 0, 0, 0);
    acc[2] = __builtin_amdgcn_mfma_f32_16x16x32_bf16(af, b2, acc[2], 0, 0, 0);
    acc[3] = __builtin_amdgcn_mfma_f32_16x16x32_bf16(af, b3, acc[3], 0, 0, 0);
  }
#pragma unroll
  for (int t = 0; t < 4; ++t) {
    int n = (wave << 6) + (t << 4) + m;
    float bv = b2f(Wb[bias_row * 256 + n]);
#pragma unroll
    for (int i = 0; i < 4; ++i) {
      int r = row0 + (q << 2) + i;
      float v = fmaxf(acc[t][i] + bv, 0.f);
      C[(size_t)r * 256 + n] = f2b(v);
    }
  }
}

// ---- last GEMM with fused mean-pool accumulation into replicated pool32.
__global__ void gemm_pool(const unsigned short* __restrict__ A,
                          const unsigned short* __restrict__ Wp,
                          const unsigned short* __restrict__ Wb, int bias_row,
                          float* __restrict__ pool32, const int* __restrict__ batch,
                          const int* __restrict__ flags, int K) {
  __shared__ int sg[16];
  const int row0 = blockIdx.x << 4;
  const int lane = threadIdx.x & 63;
  const int wave = threadIdx.x >> 6;
  float* pr = pool32 + ((blockIdx.x & (NREP - 1)) << 14);
  if (threadIdx.x < 16) {
    int r = row0 + threadIdx.x;
    sg[threadIdx.x] = flags[1] ? batch[2 * r] : batch[r];
  }
  __syncthreads();

  const int m = lane & 15;
  const int q = lane >> 4;
  f32x4 acc[4];
#pragma unroll
  for (int t = 0; t < 4; ++t) acc[t] = (f32x4){0.f, 0.f, 0.f, 0.f};

  const unsigned short* arow = A + (size_t)(row0 + m) * K + (q << 3);
  const int nb = (wave << 6) + m;
  const int kblocks = K >> 5;
  for (int kb = 0; kb < kblocks; ++kb) {
    bf16x8 af = *(const bf16x8*)(arow + (kb << 5));
    const unsigned short* wp = Wp + (((size_t)(kb << 8) + nb) * 4 + q) * 8;
    bf16x8 b0 = *(const bf16x8*)(wp);
    bf16x8 b1 = *(const bf16x8*)(wp + 512);
    bf16x8 b2 = *(const bf16x8*)(wp + 1024);
    bf16x8 b3 = *(const bf16x8*)(wp + 1536);
    acc[0] = __builtin_amdgcn_mfma_f32_16x16x32_bf16(af, b0, acc[0], 0, 0, 0);
    acc[1] = __builtin_amdgcn_mfma_f32_16x16x32_bf16(af, b1, acc[1], 0, 0, 0);
    acc[2] = __builtin_amdgcn_mfma_f32_16x16x32_bf16(af, b2, acc[2], 0, 0, 0);
    acc[3] = __builtin_amdgcn_mfma_f32_16x16x32_bf16(af, b3, acc[3], 0, 0, 0);
  }

  int uniform = (sg[0] == sg[15]);
#pragma unroll
  for (int t = 0; t < 4; ++t) {
    int n = (wave << 6) + (t << 4) + m;
    float bv = b2f(Wb[bias_row * 256 + n]);
    float v0 = fmaxf(acc[t][0] + bv, 0.f);
    float v1 = fmaxf(acc[t][1] + bv, 0.f);
    float v2 = fmaxf(acc[t][2] + bv, 0.f);
    float v3 = fmaxf(acc[t][3] + bv, 0.f);
    if (uniform) {
      float ps = v0 + v1 + v2 + v3;
      ps += __shfl_xor(ps, 16);
      ps += __shfl_xor(ps, 32);
      if (q == 0) unsafeAtomicAdd(&pr[sg[0] * 256 + n], ps);
    } else {
      int gp = sg[q << 2];
      float a = 0.f;
      float vv[4] = {v0, v1, v2, v3};
#pragma unroll
      for (int i = 0; i < 4; ++i) {
        int g = sg[(q << 2) + i];
        if (g != gp) { unsafeAtomicAdd(&pr[gp * 256 + n], a); a = 0.f; gp = g; }
        a += vv[i];
      }
      unsafeAtomicAdd(&pr[gp * 256 + n], a);
    }
  }
}

// ---- finalize: sum replicas, divide, dtype-aware store
__device__ __forceinline__ int lower_bound(const int* a, int n, int v, int is64) {
  int lo = 0, hi = n;
  while (lo < hi) {
    int mid = (lo + hi) >> 1;
    int bv = is64 ? a[2 * mid] : a[mid];
    if (bv < v) lo = mid + 1; else hi = mid;
  }
  return lo;
}

__global__ void pool_final(const float* __restrict__ pool32,
                           const int* __restrict__ batch,
                           void* __restrict__ out,
                           const int* __restrict__ flags) {
  __shared__ int sh[2];
  int g = blockIdx.x;
  int is64 = flags[1];
  if (threadIdx.x == 0) sh[0] = lower_bound(batch, N_NODES, g, is64);
  if (threadIdx.x == 1) sh[1] = lower_bound(batch, N_NODES, g + 1, is64);
  __syncthreads();
  int c = threadIdx.x;
  float s = 0.f;
#pragma unroll
  for (int r = 0; r < NREP; ++r) s += pool32[(r << 14) + g * 256 + c];
  float res = s / fmaxf((float)(sh[1] - sh[0]), 1.0f);
  if (flags[0]) ((unsigned short*)out)[(size_t)g * 256 + c] = f2b(res);
  else          ((float*)out)[(size_t)g * 256 + c] = res;
}

extern "C" void kernel_launch(void* const* d_in, const int* in_sizes, int n_in,
                              void* d_out, int out_size, void* d_ws, size_t ws_size,
                              hipStream_t stream) {
  const void* x    = d_in[0];
  const int*  ei   = (const int*)d_in[1];
  const int*  batch= (const int*)d_in[2];

  char* ws = (char*)d_ws;
  int*            flags = (int*)(ws + OFF_FLAGS);
  unsigned short* Wb    = (unsigned short*)(ws + OFF_WB);
  unsigned short* Wp0   = (unsigned short*)(ws + OFF_WP0);
  unsigned short* Wp1   = (unsigned short*)(ws + OFF_WP1);
  unsigned short* Wp2   = (unsigned short*)(ws + OFF_WP2);
  unsigned short* Wp3   = (unsigned short*)(ws + OFF_WP3);
  int*            cnts  = (int*)(ws + OFF_CNT);
  int*            rowp  = (int*)(ws + OFF_ROWPTR);
  int*            curs  = (int*)(ws + OFF_CURSOR);
  unsigned short* ssrc  = (unsigned short*)(ws + OFF_SSRC);
  unsigned short* A     = (unsigned short*)(ws + OFF_A);
  unsigned short* B     = (unsigned short*)(ws + OFF_B);
  unsigned short* C     = (unsigned short*)(ws + OFF_C);
  float*          pool32= (float*)(ws + OFF_POOL32);
  int*            bsum  = (int*)(ws + OFF_BSUM);
  int*            dcnt  = (int*)(ws + OFF_DCNT);
  int*            dcur  = (int*)(ws + OFF_DCUR);
  int*            perm  = (int*)(ws + OFF_PERM);

  detect_zero<<<513, 256, 0, stream>>>((const unsigned int*)x, (const unsigned int*)ei,
                                       flags, cnts, pool32, dcnt, dcur);
  prep_kernel<<<PB_TOTAL, 256, 0, stream>>>(x, ei,
                                            d_in[3], d_in[5], d_in[7], d_in[9],
                                            d_in[4], d_in[6], d_in[8], d_in[10],
                                            A, cnts, Wp0, Wp1, Wp2, Wp3, Wb, flags);
  scan_blocks<<<SCAN_BLOCKS, 256, 0, stream>>>(cnts, rowp, bsum, dcnt);
  scan_fix<<<SCAN_BLOCKS, 256, 0, stream>>>(rowp, curs, bsum, cnts, dcnt, dcur, perm);
  fill_kernel<<<3125, 256, 0, stream>>>(ei, curs, ssrc, flags);

  // layer 1 (feat = x directly when bf16, else converted A)
  fused_gather_gemm<<<3125, 256, 0, stream>>>(A, (const unsigned short*)x, rowp, ssrc,
                                              perm, Wp0, Wb, 0, C, 128, flags);
  gemm_relu<<<3125, 256, 0, stream>>>(C, Wp1, Wb, 1, B, 256);

  // layer 2
  fused_gather_gemm<<<3125, 256, 0, stream>>>(B, B, rowp, ssrc,
                                              perm, Wp2, Wb, 2, C, 256, flags);
  gemm_pool<<<3125, 256, 0, stream>>>(C, Wp3, Wb, 3, pool32, batch, flags, 256);

  pool_final<<<N_GRAPHS, 256, 0, stream>>>(pool32, batch, d_out, flags);
}

// Round 10
// 354.036 us; speedup vs baseline: 12.7160x; 1.0684x over previous
//
#include <hip/hip_runtime.h>

// ---------------------------------------------------------------------------
// GIN (2 layers) + global mean pool, MI355X (gfx950).
// R10: whole-MLP fusion per layer (gather -> MFMA1 -> LDS -> MFMA2 -> out),
// killing the C-buffer round trip (102 MB) and 2 dispatches; 32-lane/node
// gather for D=256 in 512-thr blocks (VGPR 48->~30; R9's 4-edge unroll
// dropped occupancy 65->45%); block-local degree sort (drops global dcnt).
// 8 dispatches.
// ---------------------------------------------------------------------------

typedef __bf16 bf16x8 __attribute__((ext_vector_type(8)));
typedef float f32x4 __attribute__((ext_vector_type(4)));

#define N_NODES 50000
#define N_EDGES 800000
#define N_GRAPHS 64
#define SCAN_BLOCKS 196
#define NREP 8

// prep kernel block ranges
#define PB_HIST0 3125
#define PB_P0    6250
#define PB_P1    6378
#define PB_P2    6634
#define PB_P3    6890
#define PB_BIAS  7146
#define PB_TOTAL 7150

#define OFF_FLAGS  0ull
#define OFF_WB     64ull
#define OFF_WP0    4096ull
#define OFF_WP1    (OFF_WP0 + 65536ull)
#define OFF_WP2    (OFF_WP1 + 131072ull)
#define OFF_WP3    (OFF_WP2 + 131072ull)
#define OFF_CNT    462848ull
#define OFF_ROWPTR 662864ull
#define OFF_CURSOR 862880ull
#define OFF_SSRC   1062912ull
#define OFF_A      2662912ull               // 12.8 MB
#define OFF_B      15462912ull              // 25.6 MB
#define OFF_POOL32 66662912ull              // 512 KB (8 replicas)
#define OFF_BSUM   67187200ull
#define OFF_PERM   67191296ull              // 200 KB

__device__ __forceinline__ float b2f(unsigned short u) {
  union { unsigned int i; float f; } v; v.i = ((unsigned int)u) << 16; return v.f;
}
__device__ __forceinline__ float b2f_lo(unsigned int u) {
  union { unsigned int i; float f; } v; v.i = u << 16; return v.f;
}
__device__ __forceinline__ float b2f_hi(unsigned int u) {
  union { unsigned int i; float f; } v; v.i = u & 0xffff0000u; return v.f;
}
__device__ __forceinline__ unsigned short f2b(float f) {
  union { unsigned int i; float f; } v; v.f = f;
  unsigned int r = v.i + 0x7fffu + ((v.i >> 16) & 1u);
  return (unsigned short)(r >> 16);
}
__device__ __forceinline__ unsigned int pk2(float hi, float lo) {
  return ((unsigned int)f2b(hi) << 16) | f2b(lo);
}
__device__ __forceinline__ void acc8(float* a, uint4 v) {
  a[0] += b2f_lo(v.x); a[1] += b2f_hi(v.x);
  a[2] += b2f_lo(v.y); a[3] += b2f_hi(v.y);
  a[4] += b2f_lo(v.z); a[5] += b2f_hi(v.z);
  a[6] += b2f_lo(v.w); a[7] += b2f_hi(v.w);
}

// ---- block 0: dtype detect; blocks 1..512: zero counts/pool32
__global__ void detect_zero(const unsigned int* __restrict__ xw,
                            const unsigned int* __restrict__ eiw,
                            int* __restrict__ flags,
                            int* __restrict__ counts, float* __restrict__ pool32) {
  if (blockIdx.x == 0) {
    __shared__ int s_f[256], s_i[256];
    int t = threadIdx.x;
    int fh = 0, iz = 0;
    for (int i = t; i < 1024; i += 256) {
      unsigned int e = (xw[i] >> 7) & 0xFFu;
      fh += (e >= 115u && e <= 130u) ? 1 : 0;
      iz += (eiw[2 * i + 1] == 0u) ? 1 : 0;
    }
    s_f[t] = fh; s_i[t] = iz;
    __syncthreads();
    for (int s = 128; s > 0; s >>= 1) {
      if (t < s) { s_f[t] += s_f[t + s]; s_i[t] += s_i[t + s]; }
      __syncthreads();
    }
    if (t == 0) { flags[0] = s_f[0] > 512 ? 1 : 0; flags[1] = s_i[0] > 512 ? 1 : 0; }
  } else {
    int i = (blockIdx.x - 1) * 256 + threadIdx.x;
    if (i < N_NODES) counts[i] = 0;
    if (i < NREP * N_GRAPHS * 256) pool32[i] = 0.f;
  }
}

// ---- prep: conv(f32 only) + edge-dst hist + 4 weight packs + bias
__device__ __forceinline__ void pack_w_elem(const void* W, unsigned short* Wp,
                                            int e, int isb) {
  int n = e & 255;
  int krow = e >> 8;
  int kb = krow >> 5, r = krow & 31;
  int q = r >> 3, j = r & 7;
  size_t out = ((((size_t)(kb << 8) + n) << 2) + q) * 8 + j;
  Wp[out] = isb ? ((const unsigned short*)W)[e] : f2b(((const float*)W)[e]);
}

__global__ void prep_kernel(const void* __restrict__ x, const int* __restrict__ ei,
                            const void* W0, const void* W1, const void* W2, const void* W3,
                            const void* b0, const void* b1, const void* b2, const void* b3,
                            unsigned short* __restrict__ A,
                            int* __restrict__ counts,
                            unsigned short* __restrict__ Wp0, unsigned short* __restrict__ Wp1,
                            unsigned short* __restrict__ Wp2, unsigned short* __restrict__ Wp3,
                            unsigned short* __restrict__ Wb,
                            const int* __restrict__ flags) {
  int b = blockIdx.x, t = threadIdx.x;
  int isb = flags[0];
  if (b < PB_HIST0) {
    if (!isb) {
      int i = b * 256 + t;
      const float4* f = (const float4*)x;
      float4 a = f[2 * i], c = f[2 * i + 1];
      ushort4 o0; o0.x = f2b(a.x); o0.y = f2b(a.y); o0.z = f2b(a.z); o0.w = f2b(a.w);
      ushort4 o1; o1.x = f2b(c.x); o1.y = f2b(c.y); o1.z = f2b(c.z); o1.w = f2b(c.w);
      ((ushort4*)A)[2 * i] = o0;
      ((ushort4*)A)[2 * i + 1] = o1;
    }
  } else if (b < PB_P0) {
    int e = (b - PB_HIST0) * 256 + t;
    int dst = flags[1] ? ei[2 * (N_EDGES + e)] : ei[N_EDGES + e];
    atomicAdd(&counts[dst], 1);
  } else if (b < PB_P1) {
    pack_w_elem(W0, Wp0, (b - PB_P0) * 256 + t, isb);
  } else if (b < PB_P2) {
    pack_w_elem(W1, Wp1, (b - PB_P1) * 256 + t, isb);
  } else if (b < PB_P3) {
    pack_w_elem(W2, Wp2, (b - PB_P2) * 256 + t, isb);
  } else if (b < PB_BIAS) {
    pack_w_elem(W3, Wp3, (b - PB_P3) * 256 + t, isb);
  } else {
    int i = (b - PB_BIAS) * 256 + t;
    const void* p = (i < 256) ? b0 : (i < 512) ? b1 : (i < 768) ? b2 : b3;
    int n = i & 255;
    Wb[i] = isb ? ((const unsigned short*)p)[n] : f2b(((const float*)p)[n]);
  }
}

// ---- scan stage 1: chunk-local scan + chunk sums
__global__ void scan_blocks(const int* __restrict__ counts,
                            int* __restrict__ rowptr, int* __restrict__ bsum) {
  __shared__ int sd[256];
  int t = threadIdx.x;
  int i = blockIdx.x * 256 + t;
  int v = (i < N_NODES) ? counts[i] : 0;
  sd[t] = v;
  __syncthreads();
  for (int off = 1; off < 256; off <<= 1) {
    int u = (t >= off) ? sd[t - off] : 0;
    __syncthreads();
    sd[t] += u;
    __syncthreads();
  }
  if (i < N_NODES) rowptr[i] = sd[t] - v;
  if (t == 255) bsum[blockIdx.x] = sd[255];
}

// ---- scan stage 2: apply chunk offsets + block-local degree sort -> perm.
// Window of 256 original nodes is counting-sorted by clamped degree; perm
// stays within the window, so tiles are degree-uniform AND span <=2 graphs.
__global__ void scan_fix(int* __restrict__ rowptr, int* __restrict__ cursor,
                         const int* __restrict__ bsum, const int* __restrict__ counts,
                         int* __restrict__ perm) {
  __shared__ int sb[256], lh[256], lc2[256];
  int t = threadIdx.x;
  sb[t] = (t < SCAN_BLOCKS) ? bsum[t] : 0;
  lh[t] = 0; lc2[t] = 0;
  __syncthreads();
  for (int off = 1; off < 256; off <<= 1) {
    int u = (t >= off) ? sb[t - off] : 0;
    __syncthreads();
    sb[t] += u;
    __syncthreads();
  }
  int boffv = (blockIdx.x > 0) ? sb[blockIdx.x - 1] : 0;
  int i = blockIdx.x * 256 + t;
  int d = 0;
  int valid = (i < N_NODES);
  if (valid) {
    int v = rowptr[i] + boffv;
    rowptr[i] = v;
    cursor[i] = v;
    int c = counts[i];
    d = c > 255 ? 255 : c;
    atomicAdd(&lh[d], 1);
  }
  if (i == 0) rowptr[N_NODES] = N_EDGES;
  __syncthreads();
  int own = lh[t];
  for (int off = 1; off < 256; off <<= 1) {
    int u = (t >= off) ? lh[t - off] : 0;
    __syncthreads();
    lh[t] += u;
    __syncthreads();
  }
  int ex = lh[t] - own;
  __syncthreads();
  lh[t] = ex;               // exclusive bucket offset, block-local
  __syncthreads();
  if (valid) {
    int r = lh[d] + atomicAdd(&lc2[d], 1);
    perm[blockIdx.x * 256 + r] = i;
  }
}

__global__ void fill_kernel(const int* __restrict__ ei, int* __restrict__ cursor,
                            unsigned short* __restrict__ ssrc,
                            const int* __restrict__ flags) {
  int e = blockIdx.x * blockDim.x + threadIdx.x;
  if (e >= N_EDGES) return;
  int is64 = flags[1];
  int src = is64 ? ei[2 * e] : ei[e];
  int dst = is64 ? ei[2 * (N_EDGES + e)] : ei[N_EDGES + e];
  int pos = atomicAdd(&cursor[dst], 1);
  ssrc[pos] = (unsigned short)src;
}

// ---- layer 1 fully fused: gather(D=128) -> t=relu(agg@W0+b0) in LDS ->
// h1=relu(t@W1+b1) -> scatter rows to B. 256 thr, tile 16 nodes.
__global__ void __launch_bounds__(256) fused_layer1(
    const unsigned short* __restrict__ featCanon,
    const unsigned short* __restrict__ featRaw,
    const int* __restrict__ rowptr, const unsigned short* __restrict__ ssrc,
    const int* __restrict__ perm,
    const unsigned short* __restrict__ Wp0, const unsigned short* __restrict__ Wp1,
    const unsigned short* __restrict__ Wb,
    unsigned short* __restrict__ B, const int* __restrict__ flags) {
  __shared__ __align__(16) unsigned short Alds[16 * 136];
  __shared__ __align__(16) unsigned short Tlds[16 * 264];
  __shared__ int sp[16];
  const int row0 = blockIdx.x << 4;
  const int lane = threadIdx.x & 63;
  const int wave = threadIdx.x >> 6;
  const unsigned short* feat = flags[0] ? featRaw : featCanon;
  if (threadIdx.x < 16) sp[threadIdx.x] = perm[row0 + threadIdx.x];
  __syncthreads();

  {  // gather: 16 lanes/node, 4-edge unroll, a[8]
    int sub = lane >> 4, l = lane & 15;
    int nl = (wave << 2) + sub;
    int node = sp[nl];
    int beg = rowptr[node], end = rowptr[node + 1];
    int c = l << 3;
    float a[8];
#pragma unroll
    for (int j = 0; j < 8; ++j) a[j] = 0.f;
    acc8(a, *(const uint4*)(feat + (size_t)node * 128 + c));
    int i = beg;
    for (; i + 3 < end; i += 4) {
      int ss[4];
#pragma unroll
      for (int e = 0; e < 4; ++e) ss[e] = ssrc[i + e];
      uint4 v[4];
#pragma unroll
      for (int e = 0; e < 4; ++e)
        v[e] = *(const uint4*)(feat + (size_t)ss[e] * 128 + c);
#pragma unroll
      for (int e = 0; e < 4; ++e) acc8(a, v[e]);
    }
    for (; i < end; ++i)
      acc8(a, *(const uint4*)(feat + (size_t)ssrc[i] * 128 + c));
    uint4 o;
    o.x = pk2(a[1], a[0]); o.y = pk2(a[3], a[2]);
    o.z = pk2(a[5], a[4]); o.w = pk2(a[7], a[6]);
    *(uint4*)(&Alds[nl * 136 + c]) = o;
  }
  __syncthreads();

  const int m = lane & 15, q = lane >> 4;
  {  // MFMA1: K=128
    f32x4 acc[4];
#pragma unroll
    for (int t = 0; t < 4; ++t) acc[t] = (f32x4){0.f, 0.f, 0.f, 0.f};
    const unsigned short* arow = &Alds[m * 136 + (q << 3)];
    const int nb = (wave << 6) + m;
#pragma unroll
    for (int kb = 0; kb < 4; ++kb) {
      bf16x8 af = *(const bf16x8*)(arow + (kb << 5));
      const unsigned short* wp = Wp0 + (((size_t)(kb << 8) + nb) * 4 + q) * 8;
      acc[0] = __builtin_amdgcn_mfma_f32_16x16x32_bf16(af, *(const bf16x8*)(wp), acc[0], 0, 0, 0);
      acc[1] = __builtin_amdgcn_mfma_f32_16x16x32_bf16(af, *(const bf16x8*)(wp + 512), acc[1], 0, 0, 0);
      acc[2] = __builtin_amdgcn_mfma_f32_16x16x32_bf16(af, *(const bf16x8*)(wp + 1024), acc[2], 0, 0, 0);
      acc[3] = __builtin_amdgcn_mfma_f32_16x16x32_bf16(af, *(const bf16x8*)(wp + 1536), acc[3], 0, 0, 0);
    }
#pragma unroll
    for (int t = 0; t < 4; ++t) {
      int n = (wave << 6) + (t << 4) + m;
      float bv = b2f(Wb[n]);                       // bias row 0
#pragma unroll
      for (int i = 0; i < 4; ++i)
        Tlds[((q << 2) + i) * 264 + n] = f2b(fmaxf(acc[t][i] + bv, 0.f));
    }
  }
  __syncthreads();

  {  // MFMA2: K=256 from Tlds
    f32x4 acc[4];
#pragma unroll
    for (int t = 0; t < 4; ++t) acc[t] = (f32x4){0.f, 0.f, 0.f, 0.f};
    const unsigned short* arow = &Tlds[m * 264 + (q << 3)];
    const int nb = (wave << 6) + m;
#pragma unroll
    for (int kb = 0; kb < 8; ++kb) {
      bf16x8 af = *(const bf16x8*)(arow + (kb << 5));
      const unsigned short* wp = Wp1 + (((size_t)(kb << 8) + nb) * 4 + q) * 8;
      acc[0] = __builtin_amdgcn_mfma_f32_16x16x32_bf16(af, *(const bf16x8*)(wp), acc[0], 0, 0, 0);
      acc[1] = __builtin_amdgcn_mfma_f32_16x16x32_bf16(af, *(const bf16x8*)(wp + 512), acc[1], 0, 0, 0);
      acc[2] = __builtin_amdgcn_mfma_f32_16x16x32_bf16(af, *(const bf16x8*)(wp + 1024), acc[2], 0, 0, 0);
      acc[3] = __builtin_amdgcn_mfma_f32_16x16x32_bf16(af, *(const bf16x8*)(wp + 1536), acc[3], 0, 0, 0);
    }
#pragma unroll
    for (int t = 0; t < 4; ++t) {
      int n = (wave << 6) + (t << 4) + m;
      float bv = b2f(Wb[256 + n]);                 // bias row 1
#pragma unroll
      for (int i = 0; i < 4; ++i) {
        int r = sp[(q << 2) + i];
        B[(size_t)r * 256 + n] = f2b(fmaxf(acc[t][i] + bv, 0.f));
      }
    }
  }
}

// ---- layer 2 fully fused: gather(D=256) -> t2 -> h2 -> pool atomics.
// 512 thr / 8 waves; 32 lanes/node (8 acc, 1 uint4/edge); tile 16 nodes.
__global__ void __launch_bounds__(512) fused_layer2(
    const unsigned short* __restrict__ B,
    const int* __restrict__ rowptr, const unsigned short* __restrict__ ssrc,
    const int* __restrict__ perm,
    const unsigned short* __restrict__ Wp2, const unsigned short* __restrict__ Wp3,
    const unsigned short* __restrict__ Wb,
    float* __restrict__ pool32, const int* __restrict__ batch,
    const int* __restrict__ flags) {
  __shared__ __align__(16) unsigned short Alds[16 * 264];
  __shared__ __align__(16) unsigned short Tlds[16 * 264];
  __shared__ int sp[16], sg[16], uni;
  const int row0 = blockIdx.x << 4;
  const int lane = threadIdx.x & 63;
  const int wave = threadIdx.x >> 6;   // 0..7
  if (threadIdx.x < 16) {
    int p = perm[row0 + threadIdx.x];
    sp[threadIdx.x] = p;
    sg[threadIdx.x] = flags[1] ? batch[2 * p] : batch[p];
  }
  __syncthreads();
  if (threadIdx.x == 0) {
    int u = 1;
#pragma unroll
    for (int i = 1; i < 16; ++i) u &= (sg[i] == sg[0]);
    uni = u;
  }

  {  // gather: 32 lanes/node, 4-edge unroll
    int sub = lane >> 5, l = lane & 31;
    int nl = (wave << 1) + sub;        // 0..15
    int node = sp[nl];
    int beg = rowptr[node], end = rowptr[node + 1];
    int c = l << 3;
    float a[8];
#pragma unroll
    for (int j = 0; j < 8; ++j) a[j] = 0.f;
    acc8(a, *(const uint4*)(B + (size_t)node * 256 + c));
    int i = beg;
    for (; i + 3 < end; i += 4) {
      int ss[4];
#pragma unroll
      for (int e = 0; e < 4; ++e) ss[e] = ssrc[i + e];
      uint4 v[4];
#pragma unroll
      for (int e = 0; e < 4; ++e)
        v[e] = *(const uint4*)(B + (size_t)ss[e] * 256 + c);
#pragma unroll
      for (int e = 0; e < 4; ++e) acc8(a, v[e]);
    }
    for (; i < end; ++i)
      acc8(a, *(const uint4*)(B + (size_t)ssrc[i] * 256 + c));
    uint4 o;
    o.x = pk2(a[1], a[0]); o.y = pk2(a[3], a[2]);
    o.z = pk2(a[5], a[4]); o.w = pk2(a[7], a[6]);
    *(uint4*)(&Alds[nl * 264 + c]) = o;
  }
  __syncthreads();

  const int m = lane & 15, q = lane >> 4;
  {  // MFMA1: K=256, each wave covers 32 cols
    f32x4 acc[2];
    acc[0] = (f32x4){0.f, 0.f, 0.f, 0.f};
    acc[1] = (f32x4){0.f, 0.f, 0.f, 0.f};
    const unsigned short* arow = &Alds[m * 264 + (q << 3)];
    const int nb = (wave << 5) + m;
#pragma unroll
    for (int kb = 0; kb < 8; ++kb) {
      bf16x8 af = *(const bf16x8*)(arow + (kb << 5));
      const unsigned short* wp = Wp2 + (((size_t)(kb << 8) + nb) * 4 + q) * 8;
      acc[0] = __builtin_amdgcn_mfma_f32_16x16x32_bf16(af, *(const bf16x8*)(wp), acc[0], 0, 0, 0);
      acc[1] = __builtin_amdgcn_mfma_f32_16x16x32_bf16(af, *(const bf16x8*)(wp + 512), acc[1], 0, 0, 0);
    }
#pragma unroll
    for (int t = 0; t < 2; ++t) {
      int n = (wave << 5) + (t << 4) + m;
      float bv = b2f(Wb[512 + n]);                 // bias row 2
#pragma unroll
      for (int i = 0; i < 4; ++i)
        Tlds[((q << 2) + i) * 264 + n] = f2b(fmaxf(acc[t][i] + bv, 0.f));
    }
  }
  __syncthreads();

  {  // MFMA2: K=256 -> pool epilogue
    f32x4 acc[2];
    acc[0] = (f32x4){0.f, 0.f, 0.f, 0.f};
    acc[1] = (f32x4){0.f, 0.f, 0.f, 0.f};
    const unsigned short* arow = &Tlds[m * 264 + (q << 3)];
    const int nb = (wave << 5) + m;
#pragma unroll
    for (int kb = 0; kb < 8; ++kb) {
      bf16x8 af = *(const bf16x8*)(arow + (kb << 5));
      const unsigned short* wp = Wp3 + (((size_t)(kb << 8) + nb) * 4 + q) * 8;
      acc[0] = __builtin_amdgcn_mfma_f32_16x16x32_bf16(af, *(const bf16x8*)(wp), acc[0], 0, 0, 0);
      acc[1] = __builtin_amdgcn_mfma_f32_16x16x32_bf16(af, *(const bf16x8*)(wp + 512), acc[1], 0, 0, 0);
    }
    float* pr = pool32 + ((blockIdx.x & (NREP - 1)) << 14);
    int u = uni;
#pragma unroll
    for (int t = 0; t < 2; ++t) {
      int n = (wave << 5) + (t << 4) + m;
      float bv = b2f(Wb[768 + n]);                 // bias row 3
      float v0 = fmaxf(acc[t][0] + bv, 0.f);
      float v1 = fmaxf(acc[t][1] + bv, 0.f);
      float v2 = fmaxf(acc[t][2] + bv, 0.f);
      float v3 = fmaxf(acc[t][3] + bv, 0.f);
      if (u) {
        float ps = v0 + v1 + v2 + v3;
        ps += __shfl_xor(ps, 16);
        ps += __shfl_xor(ps, 32);
        if (q == 0) unsafeAtomicAdd(&pr[sg[0] * 256 + n], ps);
      } else {
        float vv[4] = {v0, v1, v2, v3};
        int gp = sg[q << 2];
        float a = 0.f;
#pragma unroll
        for (int i = 0; i < 4; ++i) {
          int g = sg[(q << 2) + i];
          if (g != gp) { unsafeAtomicAdd(&pr[gp * 256 + n], a); a = 0.f; gp = g; }
          a += vv[i];
        }
        unsafeAtomicAdd(&pr[gp * 256 + n], a);
      }
    }
  }
}

// ---- finalize: sum replicas, divide, dtype-aware store
__device__ __forceinline__ int lower_bound(const int* a, int n, int v, int is64) {
  int lo = 0, hi = n;
  while (lo < hi) {
    int mid = (lo + hi) >> 1;
    int bv = is64 ? a[2 * mid] : a[mid];
    if (bv < v) lo = mid + 1; else hi = mid;
  }
  return lo;
}

__global__ void pool_final(const float* __restrict__ pool32,
                           const int* __restrict__ batch,
                           void* __restrict__ out,
                           const int* __restrict__ flags) {
  __shared__ int sh[2];
  int g = blockIdx.x;
  int is64 = flags[1];
  if (threadIdx.x == 0) sh[0] = lower_bound(batch, N_NODES, g, is64);
  if (threadIdx.x == 1) sh[1] = lower_bound(batch, N_NODES, g + 1, is64);
  __syncthreads();
  int c = threadIdx.x;
  float s = 0.f;
#pragma unroll
  for (int r = 0; r < NREP; ++r) s += pool32[(r << 14) + g * 256 + c];
  float res = s / fmaxf((float)(sh[1] - sh[0]), 1.0f);
  if (flags[0]) ((unsigned short*)out)[(size_t)g * 256 + c] = f2b(res);
  else          ((float*)out)[(size_t)g * 256 + c] = res;
}

extern "C" void kernel_launch(void* const* d_in, const int* in_sizes, int n_in,
                              void* d_out, int out_size, void* d_ws, size_t ws_size,
                              hipStream_t stream) {
  const void* x    = d_in[0];
  const int*  ei   = (const int*)d_in[1];
  const int*  batch= (const int*)d_in[2];

  char* ws = (char*)d_ws;
  int*            flags = (int*)(ws + OFF_FLAGS);
  unsigned short* Wb    = (unsigned short*)(ws + OFF_WB);
  unsigned short* Wp0   = (unsigned short*)(ws + OFF_WP0);
  unsigned short* Wp1   = (unsigned short*)(ws + OFF_WP1);
  unsigned short* Wp2   = (unsigned short*)(ws + OFF_WP2);
  unsigned short* Wp3   = (unsigned short*)(ws + OFF_WP3);
  int*            cnts  = (int*)(ws + OFF_CNT);
  int*            rowp  = (int*)(ws + OFF_ROWPTR);
  int*            curs  = (int*)(ws + OFF_CURSOR);
  unsigned short* ssrc  = (unsigned short*)(ws + OFF_SSRC);
  unsigned short* A     = (unsigned short*)(ws + OFF_A);
  unsigned short* B     = (unsigned short*)(ws + OFF_B);
  float*          pool32= (float*)(ws + OFF_POOL32);
  int*            bsum  = (int*)(ws + OFF_BSUM);
  int*            perm  = (int*)(ws + OFF_PERM);

  detect_zero<<<513, 256, 0, stream>>>((const unsigned int*)x, (const unsigned int*)ei,
                                       flags, cnts, pool32);
  prep_kernel<<<PB_TOTAL, 256, 0, stream>>>(x, ei,
                                            d_in[3], d_in[5], d_in[7], d_in[9],
                                            d_in[4], d_in[6], d_in[8], d_in[10],
                                            A, cnts, Wp0, Wp1, Wp2, Wp3, Wb, flags);
  scan_blocks<<<SCAN_BLOCKS, 256, 0, stream>>>(cnts, rowp, bsum);
  scan_fix<<<SCAN_BLOCKS, 256, 0, stream>>>(rowp, curs, bsum, cnts, perm);
  fill_kernel<<<3125, 256, 0, stream>>>(ei, curs, ssrc, flags);

  fused_layer1<<<3125, 256, 0, stream>>>(A, (const unsigned short*)x, rowp, ssrc,
                                         perm, Wp0, Wp1, Wb, B, flags);
  fused_layer2<<<3125, 512, 0, stream>>>(B, rowp, ssrc, perm, Wp2, Wp3, Wb,
                                         pool32, batch, flags);

  pool_final<<<N_GRAPHS, 256, 0, stream>>>(pool32, batch, d_out, flags);
}